// Round 13
// baseline (252.974 us; speedup 1.0000x reference)
//
#include <hip/hip_runtime.h>

#define NN 50000
#define NPAD 50176   // NN rounded up to 49*1024 (scan int4 loads)
#define MPAD 50048   // 782*64 (GEMM row tiles)
#define NE 800000
#define BN_EPS 1e-5f

#define NSEG 782     // edge chunks of 1024
#define NBKT 49      // dst buckets of 1024 nodes

typedef __attribute__((ext_vector_type(8))) short bf16x8;
typedef __attribute__((ext_vector_type(4))) float f32x4;

__device__ __forceinline__ void atomAddF(float* p, float v) { unsafeAtomicAdd(p, v); }

__device__ __forceinline__ float bf2f(ushort u) {
    union { uint i; float f; } v; v.i = ((uint)u) << 16; return v.f;
}
__device__ __forceinline__ ushort f2bf(float f) {
    union { uint i; float f; } v; v.f = f;
    uint u = v.i;
    return (ushort)((u + 0x7FFFu + ((u >> 16) & 1u)) >> 16);  // RNE
}

// ---- fill phase 1: per-block counting sort of 1024 edges by dst-bucket ----
__global__ __launch_bounds__(256) void k_part(const int* __restrict__ ei,
                                              int* __restrict__ cnt,
                                              int2* __restrict__ seg,
                                              int* __restrict__ cnt2,
                                              int* __restrict__ boff2) {
    __shared__ int lcnt[NBKT];
    __shared__ int lboff[NBKT];
    __shared__ int2 lbuf[1024];
    const int b = blockIdx.x, t = threadIdx.x;
    if (t < NBKT) lcnt[t] = 0;
    __syncthreads();
    int src[4], dst[4], rk[4], bkt[4];
    const int e0 = b * 1024;
    #pragma unroll
    for (int j = 0; j < 4; ++j) {
        int e = e0 + t + j * 256;
        if (e < NE) {
            src[j] = ei[e];
            dst[j] = ei[NE + e];
            bkt[j] = dst[j] >> 10;
            rk[j] = atomicAdd(&lcnt[bkt[j]], 1);
            atomicAdd(&cnt[dst[j]], 1);          // fused degree count
        } else rk[j] = -1;
    }
    __syncthreads();
    if (t < 64) {  // wave 0: exclusive scan of 49 bucket counts
        int v = (t < NBKT) ? lcnt[t] : 0;
        int x = v;
        #pragma unroll
        for (int off = 1; off < 64; off <<= 1) {
            int y = __shfl_up(x, off);
            if (t >= off) x += y;
        }
        if (t < NBKT) lboff[t] = x - v;
    }
    __syncthreads();
    #pragma unroll
    for (int j = 0; j < 4; ++j)
        if (rk[j] >= 0) lbuf[lboff[bkt[j]] + rk[j]] = make_int2(src[j], dst[j]);
    __syncthreads();
    const int total = lboff[NBKT - 1] + lcnt[NBKT - 1];
    for (int i = t; i < total; i += 256) seg[e0 + i] = lbuf[i];   // coalesced
    if (t < NBKT) { cnt2[b * NBKT + t] = lcnt[t]; boff2[b * NBKT + t] = lboff[t]; }
}

// ---- fill phase 2: one block per bucket; LDS ranks; writes confined to bucket window ----
__global__ __launch_bounds__(1024) void k_rank(const int2* __restrict__ seg,
                                               const int* __restrict__ cnt2,
                                               const int* __restrict__ boff2,
                                               const int* __restrict__ rowptr,
                                               int* __restrict__ csr_src) {
    __shared__ int lrk[1024];
    const int k = blockIdx.x, t = threadIdx.x;
    lrk[t] = 0;
    __syncthreads();
    const int node0 = k << 10;
    const int g = t >> 3, l = t & 7;   // 128 groups x 8 lanes
    for (int b = g; b < NSEG; b += 128) {
        const int n = cnt2[b * NBKT + k];
        const int base = b * 1024 + boff2[b * NBKT + k];
        for (int i = l; i < n; i += 8) {
            int2 e = seg[base + i];
            int rank = atomicAdd(&lrk[e.y - node0], 1);
            csr_src[rowptr[e.y] + rank] = e.x;
        }
    }
}

// ---- CSR scan phase A ----
__global__ __launch_bounds__(256) void k_scanA(const int* __restrict__ cnt,
                                               int* __restrict__ locpre, int* __restrict__ bsum) {
    const int b = blockIdx.x, t = threadIdx.x;
    const int base = b * 1024 + t * 4;
    int4 v = *reinterpret_cast<const int4*>(&cnt[base]);
    int s = v.x + v.y + v.z + v.w;
    __shared__ int sm[256];
    sm[t] = s;
    __syncthreads();
    for (int off = 1; off < 256; off <<= 1) {
        int y = (t >= off) ? sm[t - off] : 0;
        __syncthreads();
        sm[t] += y;
        __syncthreads();
    }
    int excl = sm[t] - s;
    locpre[base + 0] = excl;
    locpre[base + 1] = excl + v.x;
    locpre[base + 2] = excl + v.x + v.y;
    locpre[base + 3] = excl + v.x + v.y + v.z;
    if (t == 255) bsum[b] = sm[255];
}

// ---- CSR scan phase C ----
__global__ __launch_bounds__(256) void k_scanC(const int* __restrict__ cnt,
                                               const int* __restrict__ locpre,
                                               const int* __restrict__ bsum,
                                               int* __restrict__ rowptr,
                                               float* __restrict__ invc) {
    __shared__ int sm[64];
    const int b = blockIdx.x, t = threadIdx.x;
    const int nb = NPAD / 1024;  // 49
    if (t < nb) sm[t] = bsum[t];
    __syncthreads();
    int off = 0;
    for (int j = 0; j < b; ++j) off += sm[j];
    const int base = b * 1024 + t * 4;
    #pragma unroll
    for (int k = 0; k < 4; ++k) {
        int i = base + k;
        if (i < NN) {
            rowptr[i] = locpre[i] + off;
            invc[i] = 1.0f / fmaxf((float)cnt[i], 1.0f);
        }
    }
    if (b == 0 && t == 0) rowptr[NN] = NE;
}

// ---- prep: cast x -> bf16 + transposed bf16 weights ----
__global__ __launch_bounds__(256) void k_prep(const float* __restrict__ x, ushort* __restrict__ xb,
                                              const float* __restrict__ W1l, const float* __restrict__ W1r,
                                              const float* __restrict__ W2l, const float* __restrict__ W2r,
                                              ushort* __restrict__ Wt1, ushort* __restrict__ Wt2) {
    if (blockIdx.x < 3125) {
        unsigned g = blockIdx.x * 256u + threadIdx.x;  // < 800000 exactly
        const float4* p = reinterpret_cast<const float4*>(x) + (size_t)g * 2;
        float4 a = p[0], b = p[1];
        uint4 w;
        w.x = (uint)f2bf(a.x) | ((uint)f2bf(a.y) << 16);
        w.y = (uint)f2bf(a.z) | ((uint)f2bf(a.w) << 16);
        w.z = (uint)f2bf(b.x) | ((uint)f2bf(b.y) << 16);
        w.w = (uint)f2bf(b.z) | ((uint)f2bf(b.w) << 16);
        *reinterpret_cast<uint4*>(&xb[(size_t)g * 8]) = w;
    } else {
        int g = (blockIdx.x - 3125) * 256 + threadIdx.x;  // < 131072 exactly
        if (g < 65536) {
            int n = g >> 8, k = g & 255;
            float v = (k < 128) ? W1l[k * 256 + n] : W1r[(k - 128) * 256 + n];
            Wt1[n * 256 + k] = f2bf(v);
        } else {
            int g2 = g - 65536;
            int n = g2 >> 8, k = g2 & 255;
            float v = (n < 128) ? W2l[k * 128 + n] : W2r[k * 128 + (n - 128)];
            Wt2[n * 256 + k] = f2bf(v);
        }
    }
}

// ---- gather-aggregate over 128-ch bf16 rows, 4-way edge-parallel, 4x unrolled ----
template <bool FINAL>
__global__ __launch_bounds__(256) void k_agg128(const ushort* __restrict__ feat,
                                                const int* __restrict__ rowptr,
                                                const int* __restrict__ csr_src,
                                                const float* __restrict__ invc,
                                                const float* __restrict__ z,
                                                const float* __restrict__ bias,
                                                ushort* __restrict__ aggb,
                                                float* __restrict__ outf) {
    int gw = (blockIdx.x * 256 + threadIdx.x) >> 6;
    int lane = threadIdx.x & 63;
    if (gw >= NN) return;
    const int grp = lane >> 4, sl = lane & 15;
    const int beg = rowptr[gw], end = rowptr[gw + 1];
    float acc[8] = {};
    int e = beg + grp;
    for (; e + 12 < end; e += 16) {
        int s0 = csr_src[e];
        int s1 = csr_src[e + 4];
        int s2 = csr_src[e + 8];
        int s3 = csr_src[e + 12];
        uint4 u0 = *reinterpret_cast<const uint4*>(&feat[(size_t)s0 * 128 + sl * 8]);
        uint4 u1 = *reinterpret_cast<const uint4*>(&feat[(size_t)s1 * 128 + sl * 8]);
        uint4 u2 = *reinterpret_cast<const uint4*>(&feat[(size_t)s2 * 128 + sl * 8]);
        uint4 u3 = *reinterpret_cast<const uint4*>(&feat[(size_t)s3 * 128 + sl * 8]);
        acc[0] += bf2f((ushort)u0.x) + bf2f((ushort)u1.x) + bf2f((ushort)u2.x) + bf2f((ushort)u3.x);
        acc[1] += bf2f((ushort)(u0.x >> 16)) + bf2f((ushort)(u1.x >> 16)) + bf2f((ushort)(u2.x >> 16)) + bf2f((ushort)(u3.x >> 16));
        acc[2] += bf2f((ushort)u0.y) + bf2f((ushort)u1.y) + bf2f((ushort)u2.y) + bf2f((ushort)u3.y);
        acc[3] += bf2f((ushort)(u0.y >> 16)) + bf2f((ushort)(u1.y >> 16)) + bf2f((ushort)(u2.y >> 16)) + bf2f((ushort)(u3.y >> 16));
        acc[4] += bf2f((ushort)u0.z) + bf2f((ushort)u1.z) + bf2f((ushort)u2.z) + bf2f((ushort)u3.z);
        acc[5] += bf2f((ushort)(u0.z >> 16)) + bf2f((ushort)(u1.z >> 16)) + bf2f((ushort)(u2.z >> 16)) + bf2f((ushort)(u3.z >> 16));
        acc[6] += bf2f((ushort)u0.w) + bf2f((ushort)u1.w) + bf2f((ushort)u2.w) + bf2f((ushort)u3.w);
        acc[7] += bf2f((ushort)(u0.w >> 16)) + bf2f((ushort)(u1.w >> 16)) + bf2f((ushort)(u2.w >> 16)) + bf2f((ushort)(u3.w >> 16));
    }
    for (; e < end; e += 4) {
        int s0 = csr_src[e];
        uint4 u0 = *reinterpret_cast<const uint4*>(&feat[(size_t)s0 * 128 + sl * 8]);
        acc[0] += bf2f((ushort)u0.x); acc[1] += bf2f((ushort)(u0.x >> 16));
        acc[2] += bf2f((ushort)u0.y); acc[3] += bf2f((ushort)(u0.y >> 16));
        acc[4] += bf2f((ushort)u0.z); acc[5] += bf2f((ushort)(u0.z >> 16));
        acc[6] += bf2f((ushort)u0.w); acc[7] += bf2f((ushort)(u0.w >> 16));
    }
    #pragma unroll
    for (int i = 0; i < 8; ++i) {
        acc[i] += __shfl_xor(acc[i], 16);
        acc[i] += __shfl_xor(acc[i], 32);
    }
    if (grp == 0) {
        const float ic = invc[gw];
        if constexpr (FINAL) {
            const float* zp = &z[(size_t)gw * 128 + sl * 8];
            float4 z0 = *reinterpret_cast<const float4*>(zp);
            float4 z1 = *reinterpret_cast<const float4*>(zp + 4);
            float4 b0 = *reinterpret_cast<const float4*>(&bias[sl * 8]);
            float4 b1 = *reinterpret_cast<const float4*>(&bias[sl * 8 + 4]);
            float4 o0, o1;
            o0.x = fmaf(acc[0], ic, z0.x + b0.x);
            o0.y = fmaf(acc[1], ic, z0.y + b0.y);
            o0.z = fmaf(acc[2], ic, z0.z + b0.z);
            o0.w = fmaf(acc[3], ic, z0.w + b0.w);
            o1.x = fmaf(acc[4], ic, z1.x + b1.x);
            o1.y = fmaf(acc[5], ic, z1.y + b1.y);
            o1.z = fmaf(acc[6], ic, z1.z + b1.z);
            o1.w = fmaf(acc[7], ic, z1.w + b1.w);
            float* op = &outf[(size_t)gw * 128 + sl * 8];
            *reinterpret_cast<float4*>(op) = o0;
            *reinterpret_cast<float4*>(op + 4) = o1;
        } else {
            uint4 o;
            o.x = (uint)f2bf(acc[0] * ic) | ((uint)f2bf(acc[1] * ic) << 16);
            o.y = (uint)f2bf(acc[2] * ic) | ((uint)f2bf(acc[3] * ic) << 16);
            o.z = (uint)f2bf(acc[4] * ic) | ((uint)f2bf(acc[5] * ic) << 16);
            o.w = (uint)f2bf(acc[6] * ic) | ((uint)f2bf(acc[7] * ic) << 16);
            *reinterpret_cast<uint4*>(&aggb[(size_t)gw * 128 + sl * 8]) = o;
        }
    }
}

// ---- MFMA GEMM: out = [A1 | A2] @ Wt^T (+bias) ----
// 64x128 tile, 4 waves (2x2), wave tile 32x64, BK=32.
// A: LDS double-buffered (stride-40 pad), ONE barrier per K-iter.
// B: NO LDS — direct L2 fragment loads from Wt (128KB hot set), prefetched 1 iter ahead.
template <int K1, int K2, int NC, bool STATS, bool BN1, int OUTMODE>
__global__ __launch_bounds__(256, 2) void k_mm(const ushort* __restrict__ A1,
                                               const ushort* __restrict__ A2,
                                               const ushort* __restrict__ Wt,
                                               const float* __restrict__ bias,
                                               const float* __restrict__ sc,
                                               const float* __restrict__ sh,
                                               float* __restrict__ bnsums,
                                               ushort* __restrict__ outb,
                                               float* __restrict__ outf) {
    constexpr int KT = K1 + K2;
    constexpr int NIT = KT / 32;
    __shared__ ushort As[2][64 * 40];
    __shared__ float sred[2][4][16][2];
    const int t = threadIdx.x;
    const int lane = t & 63, wid = t >> 6;
    const int wr = wid >> 1, wc = wid & 1;
    const int r0 = blockIdx.x * 64, c0 = blockIdx.y * 128;
    const int lr = lane & 15, lg = lane >> 4;
    const int arow = t >> 2, akq = t & 3;   // A stage: 1 bf16x8 per thread

    auto aload = [&](int it) -> bf16x8 {
        const int kt = it * 32;
        const ushort* Ap = (kt < K1) ? A1 : A2;
        const int AK = (kt < K1) ? K1 : K2;
        const int ak = (kt < K1) ? kt : kt - K1;
        return *reinterpret_cast<const bf16x8*>(&Ap[(size_t)(r0 + arow) * AK + ak + akq * 8]);
    };
    auto astage = [&](int it, bf16x8 va, int buf) {
        if constexpr (BN1) {   // only used with K2==0 (ak == it*32)
            const int cb = it * 32 + akq * 8;
            float4 s0 = *reinterpret_cast<const float4*>(&sc[cb]);
            float4 s1 = *reinterpret_cast<const float4*>(&sc[cb + 4]);
            float4 h0 = *reinterpret_cast<const float4*>(&sh[cb]);
            float4 h1 = *reinterpret_cast<const float4*>(&sh[cb + 4]);
            float fsv[8] = {s0.x, s0.y, s0.z, s0.w, s1.x, s1.y, s1.z, s1.w};
            float fhv[8] = {h0.x, h0.y, h0.z, h0.w, h1.x, h1.y, h1.z, h1.w};
            #pragma unroll
            for (int j = 0; j < 8; ++j) {
                float f = bf2f((ushort)va[j]);
                f = fmaxf(fmaf(f, fsv[j], fhv[j]), 0.f);
                va[j] = (short)f2bf(f);
            }
        }
        *reinterpret_cast<bf16x8*>(&As[buf][arow * 40 + akq * 8]) = va;
    };
    auto bfrag = [&](int it, int nj) -> bf16x8 {
        const int col = c0 + wc * 64 + nj * 16 + lr;
        return *reinterpret_cast<const bf16x8*>(&Wt[(size_t)col * KT + it * 32 + lg * 8]);
    };

    f32x4 acc[2][4] = {};
    bf16x8 bcur[4], bnxt[4];

    astage(0, aload(0), 0);
    #pragma unroll
    for (int nj = 0; nj < 4; ++nj) bcur[nj] = bfrag(0, nj);
    __syncthreads();

    for (int it = 0; it < NIT; ++it) {
        const bool more = (it + 1 < NIT);
        bf16x8 na;
        if (more) {
            na = aload(it + 1);
            #pragma unroll
            for (int nj = 0; nj < 4; ++nj) bnxt[nj] = bfrag(it + 1, nj);
        }
        bf16x8 af[2];
        #pragma unroll
        for (int mi = 0; mi < 2; ++mi)
            af[mi] = *reinterpret_cast<bf16x8*>(&As[it & 1][(wr * 32 + mi * 16 + lr) * 40 + lg * 8]);
        #pragma unroll
        for (int mi = 0; mi < 2; ++mi)
            #pragma unroll
            for (int nj = 0; nj < 4; ++nj)
                acc[mi][nj] = __builtin_amdgcn_mfma_f32_16x16x32_bf16(af[mi], bcur[nj], acc[mi][nj], 0, 0, 0);
        if (more) {
            astage(it + 1, na, (it + 1) & 1);   // other buffer: no race with current reads
            __syncthreads();                    // publish for next iter
            #pragma unroll
            for (int nj = 0; nj < 4; ++nj) bcur[nj] = bnxt[nj];
        }
    }

    float ssum[4] = {}, s2sum[4] = {};
    #pragma unroll
    for (int nj = 0; nj < 4; ++nj) {
        const int col = c0 + wc * 64 + nj * 16 + lr;
        float bv = 0.f;
        if constexpr (OUTMODE == 0) bv = bias[col];
        #pragma unroll
        for (int mi = 0; mi < 2; ++mi) {
            const int rbase = r0 + wr * 32 + mi * 16;
            if (rbase + 16 > NN) continue;
            #pragma unroll
            for (int reg = 0; reg < 4; ++reg) {
                const int row = rbase + lg * 4 + reg;
                float d = acc[mi][nj][reg] + bv;
                if constexpr (STATS) { ssum[nj] += d; s2sum[nj] += d * d; }
                if constexpr (OUTMODE == 0) {
                    outb[(size_t)row * NC + col] = f2bf(d);
                } else {
                    if (col < 128) outb[(size_t)row * 128 + col] = f2bf(d);
                    else outf[(size_t)row * 128 + (col - 128)] = d;
                }
            }
        }
    }
    if constexpr (STATS) {
        #pragma unroll
        for (int nj = 0; nj < 4; ++nj) {
            ssum[nj] += __shfl_xor(ssum[nj], 16); ssum[nj] += __shfl_xor(ssum[nj], 32);
            s2sum[nj] += __shfl_xor(s2sum[nj], 16); s2sum[nj] += __shfl_xor(s2sum[nj], 32);
        }
        if (wr == 0 && lane < 16) {
            #pragma unroll
            for (int nj = 0; nj < 4; ++nj) {
                sred[wc][nj][lane][0] = ssum[nj];
                sred[wc][nj][lane][1] = s2sum[nj];
            }
        }
        __syncthreads();
        if (wr == 1 && lane < 16) {
            #pragma unroll
            for (int nj = 0; nj < 4; ++nj) {
                const int col = c0 + wc * 64 + nj * 16 + lane;
                atomAddF(&bnsums[col], ssum[nj] + sred[wc][nj][lane][0]);
                atomAddF(&bnsums[256 + col], s2sum[nj] + sred[wc][nj][lane][1]);
            }
        }
    }
}

// ---- BN finalize ----
__global__ void k_bnfin(const float* __restrict__ sums, const float* __restrict__ gamma,
                        const float* __restrict__ beta, float* __restrict__ sc,
                        float* __restrict__ sh) {
    int c = threadIdx.x;
    float mu = sums[c] * (1.0f / NN);
    float var = sums[256 + c] * (1.0f / NN) - mu * mu;
    float s = gamma[c] * rsqrtf(var + BN_EPS);
    sc[c] = s;
    sh[c] = beta[c] - mu * s;
}

extern "C" void kernel_launch(void* const* d_in, const int* in_sizes, int n_in,
                              void* d_out, int out_size, void* d_ws, size_t ws_size,
                              hipStream_t stream) {
    const float* x    = (const float*)d_in[0];
    const int*   ei   = (const int*)d_in[1];
    const float* W1l  = (const float*)d_in[2];
    const float* b1l  = (const float*)d_in[3];
    const float* W1r  = (const float*)d_in[4];
    const float* gam1 = (const float*)d_in[5];
    const float* bet1 = (const float*)d_in[6];
    const float* W2l  = (const float*)d_in[7];
    const float* b2l  = (const float*)d_in[8];
    const float* W2r  = (const float*)d_in[9];
    float* out = (float*)d_out;

    char* p = (char*)d_ws;
    ushort* xb   = (ushort*)p; p += (size_t)MPAD * 128 * 2;
    ushort* hb   = (ushort*)p; p += (size_t)MPAD * 256 * 2;
    ushort* aggb = (ushort*)p; p += (size_t)MPAD * 128 * 2;
    ushort* y2b  = (ushort*)p; p += (size_t)MPAD * 128 * 2;
    float*  zf   = (float*)p;  p += (size_t)MPAD * 128 * 4;
    ushort* Wt1  = (ushort*)p; p += 256 * 256 * 2;
    ushort* Wt2  = (ushort*)p; p += 256 * 256 * 2;
    int*   cnt    = (int*)p;   p += (size_t)NPAD * 4;
    float* bnsums = (float*)p; p += 512 * 4;
    float* bnsc   = (float*)p; p += 256 * 4;
    float* bnsh   = (float*)p; p += 256 * 4;
    float* invc   = (float*)p; p += (size_t)NPAD * 4;
    int*   rowptr = (int*)p;   p += (size_t)(NPAD + 4) * 4;
    int*   csr_src= (int*)p;   p += (size_t)NE * 4;
    int2*  seg    = (int2*)p;  p += (size_t)NE * 8;
    int*   cnt2   = (int*)p;   p += (size_t)NSEG * NBKT * 4;
    int*   boff2  = (int*)p;   p += (size_t)NSEG * NBKT * 4;
    int*   bsum   = (int*)p;   p += 64 * 4;
    int*   locpre = (int*)aggb;  // overlay: consumed by k_scanC before aggb written

    hipMemsetAsync(cnt, 0, (size_t)NPAD * 4 + 4096, stream);

    // CSR build: partition-sort (fused degree) -> scan -> ranked fill
    k_part<<<NSEG, 256, 0, stream>>>(ei, cnt, seg, cnt2, boff2);
    k_scanA<<<NPAD / 1024, 256, 0, stream>>>(cnt, locpre, bsum);
    k_scanC<<<NPAD / 1024, 256, 0, stream>>>(cnt, locpre, bsum, rowptr, invc);
    k_rank<<<NBKT, 1024, 0, stream>>>(seg, cnt2, boff2, rowptr, csr_src);

    // bf16 precompute (castx + weight transpose fused)
    k_prep<<<3637, 256, 0, stream>>>(x, xb, W1l, W1r, W2l, W2r, Wt1, Wt2);

    // Layer 1: agg(x) -> GEMM [agg|x]@Wt1 (+bias, BN stats) -> bnfin
    k_agg128<false><<<12500, 256, 0, stream>>>(xb, rowptr, csr_src, invc, nullptr, nullptr, aggb, nullptr);
    k_mm<128, 128, 256, true, false, 0><<<dim3(782, 2), 256, 0, stream>>>(
        aggb, xb, Wt1, b1l, nullptr, nullptr, bnsums, hb, nullptr);
    k_bnfin<<<1, 256, 0, stream>>>(bnsums, gam1, bet1, bnsc, bnsh);

    // Layer 2 (swapped): [y2|z] = relu(bn(h)) @ [W2l|W2r]; out = mean(y2[src]) + z + b
    k_mm<256, 0, 256, false, true, 1><<<dim3(782, 2), 256, 0, stream>>>(
        hb, nullptr, Wt2, nullptr, bnsc, bnsh, nullptr, y2b, zf);
    k_agg128<true><<<12500, 256, 0, stream>>>(y2b, rowptr, csr_src, invc, zf, b2l, nullptr, out);
}

// Round 14
// 228.058 us; speedup vs baseline: 1.1093x; 1.1093x over previous
//
#include <hip/hip_runtime.h>

#define NN 50000
#define NPAD 50176   // NN rounded up to 49*1024 (scan int4 loads)
#define MPAD 50048   // 782*64 (GEMM row tiles)
#define NE 800000
#define BN_EPS 1e-5f

#define NSEG 782     // edge chunks of 1024
#define NBKT 49      // dst buckets of 1024 nodes

typedef __attribute__((ext_vector_type(8))) short bf16x8;
typedef __attribute__((ext_vector_type(4))) float f32x4;

__device__ __forceinline__ void atomAddF(float* p, float v) { unsafeAtomicAdd(p, v); }

__device__ __forceinline__ float bf2f(ushort u) {
    union { uint i; float f; } v; v.i = ((uint)u) << 16; return v.f;
}
__device__ __forceinline__ ushort f2bf(float f) {
    union { uint i; float f; } v; v.f = f;
    uint u = v.i;
    return (ushort)((u + 0x7FFFu + ((u >> 16) & 1u)) >> 16);  // RNE
}

// ---- fill phase 1: per-block counting sort of 1024 edges by dst-bucket ----
__global__ __launch_bounds__(256) void k_part(const int* __restrict__ ei,
                                              int* __restrict__ cnt,
                                              int2* __restrict__ seg,
                                              int* __restrict__ cnt2,
                                              int* __restrict__ boff2) {
    __shared__ int lcnt[NBKT];
    __shared__ int lboff[NBKT];
    __shared__ int2 lbuf[1024];
    const int b = blockIdx.x, t = threadIdx.x;
    if (t < NBKT) lcnt[t] = 0;
    __syncthreads();
    int src[4], dst[4], rk[4], bkt[4];
    const int e0 = b * 1024;
    #pragma unroll
    for (int j = 0; j < 4; ++j) {
        int e = e0 + t + j * 256;
        if (e < NE) {
            src[j] = ei[e];
            dst[j] = ei[NE + e];
            bkt[j] = dst[j] >> 10;
            rk[j] = atomicAdd(&lcnt[bkt[j]], 1);
            atomicAdd(&cnt[dst[j]], 1);          // fused degree count
        } else rk[j] = -1;
    }
    __syncthreads();
    if (t < 64) {  // wave 0: exclusive scan of 49 bucket counts
        int v = (t < NBKT) ? lcnt[t] : 0;
        int x = v;
        #pragma unroll
        for (int off = 1; off < 64; off <<= 1) {
            int y = __shfl_up(x, off);
            if (t >= off) x += y;
        }
        if (t < NBKT) lboff[t] = x - v;
    }
    __syncthreads();
    #pragma unroll
    for (int j = 0; j < 4; ++j)
        if (rk[j] >= 0) lbuf[lboff[bkt[j]] + rk[j]] = make_int2(src[j], dst[j]);
    __syncthreads();
    const int total = lboff[NBKT - 1] + lcnt[NBKT - 1];
    for (int i = t; i < total; i += 256) seg[e0 + i] = lbuf[i];   // coalesced
    if (t < NBKT) { cnt2[b * NBKT + t] = lcnt[t]; boff2[b * NBKT + t] = lboff[t]; }
}

// ---- fill phase 2: one block per bucket; LDS ranks; writes confined to bucket window ----
__global__ __launch_bounds__(1024) void k_rank(const int2* __restrict__ seg,
                                               const int* __restrict__ cnt2,
                                               const int* __restrict__ boff2,
                                               const int* __restrict__ rowptr,
                                               int* __restrict__ csr_src) {
    __shared__ int lrk[1024];
    const int k = blockIdx.x, t = threadIdx.x;
    lrk[t] = 0;
    __syncthreads();
    const int node0 = k << 10;
    const int g = t >> 3, l = t & 7;   // 128 groups x 8 lanes
    for (int b = g; b < NSEG; b += 128) {
        const int n = cnt2[b * NBKT + k];
        const int base = b * 1024 + boff2[b * NBKT + k];
        for (int i = l; i < n; i += 8) {
            int2 e = seg[base + i];
            int rank = atomicAdd(&lrk[e.y - node0], 1);
            csr_src[rowptr[e.y] + rank] = e.x;
        }
    }
}

// ---- CSR scan phase A ----
__global__ __launch_bounds__(256) void k_scanA(const int* __restrict__ cnt,
                                               int* __restrict__ locpre, int* __restrict__ bsum) {
    const int b = blockIdx.x, t = threadIdx.x;
    const int base = b * 1024 + t * 4;
    int4 v = *reinterpret_cast<const int4*>(&cnt[base]);
    int s = v.x + v.y + v.z + v.w;
    __shared__ int sm[256];
    sm[t] = s;
    __syncthreads();
    for (int off = 1; off < 256; off <<= 1) {
        int y = (t >= off) ? sm[t - off] : 0;
        __syncthreads();
        sm[t] += y;
        __syncthreads();
    }
    int excl = sm[t] - s;
    locpre[base + 0] = excl;
    locpre[base + 1] = excl + v.x;
    locpre[base + 2] = excl + v.x + v.y;
    locpre[base + 3] = excl + v.x + v.y + v.z;
    if (t == 255) bsum[b] = sm[255];
}

// ---- CSR scan phase C ----
__global__ __launch_bounds__(256) void k_scanC(const int* __restrict__ cnt,
                                               const int* __restrict__ locpre,
                                               const int* __restrict__ bsum,
                                               int* __restrict__ rowptr,
                                               float* __restrict__ invc) {
    __shared__ int sm[64];
    const int b = blockIdx.x, t = threadIdx.x;
    const int nb = NPAD / 1024;  // 49
    if (t < nb) sm[t] = bsum[t];
    __syncthreads();
    int off = 0;
    for (int j = 0; j < b; ++j) off += sm[j];
    const int base = b * 1024 + t * 4;
    #pragma unroll
    for (int k = 0; k < 4; ++k) {
        int i = base + k;
        if (i < NN) {
            rowptr[i] = locpre[i] + off;
            invc[i] = 1.0f / fmaxf((float)cnt[i], 1.0f);
        }
    }
    if (b == 0 && t == 0) rowptr[NN] = NE;
}

// ---- prep: cast x -> bf16 + transposed bf16 weights ----
__global__ __launch_bounds__(256) void k_prep(const float* __restrict__ x, ushort* __restrict__ xb,
                                              const float* __restrict__ W1l, const float* __restrict__ W1r,
                                              const float* __restrict__ W2l, const float* __restrict__ W2r,
                                              ushort* __restrict__ Wt1, ushort* __restrict__ Wt2) {
    if (blockIdx.x < 3125) {
        unsigned g = blockIdx.x * 256u + threadIdx.x;  // < 800000 exactly
        const float4* p = reinterpret_cast<const float4*>(x) + (size_t)g * 2;
        float4 a = p[0], b = p[1];
        uint4 w;
        w.x = (uint)f2bf(a.x) | ((uint)f2bf(a.y) << 16);
        w.y = (uint)f2bf(a.z) | ((uint)f2bf(a.w) << 16);
        w.z = (uint)f2bf(b.x) | ((uint)f2bf(b.y) << 16);
        w.w = (uint)f2bf(b.z) | ((uint)f2bf(b.w) << 16);
        *reinterpret_cast<uint4*>(&xb[(size_t)g * 8]) = w;
    } else {
        int g = (blockIdx.x - 3125) * 256 + threadIdx.x;  // < 131072 exactly
        if (g < 65536) {
            int n = g >> 8, k = g & 255;
            float v = (k < 128) ? W1l[k * 256 + n] : W1r[(k - 128) * 256 + n];
            Wt1[n * 256 + k] = f2bf(v);
        } else {
            int g2 = g - 65536;
            int n = g2 >> 8, k = g2 & 255;
            float v = (n < 128) ? W2l[k * 128 + n] : W2r[k * 128 + (n - 128)];
            Wt2[n * 256 + k] = f2bf(v);
        }
    }
}

// ---- gather-aggregate over 128-ch bf16 rows, 4-way edge-parallel, 4x unrolled ----
template <bool FINAL>
__global__ __launch_bounds__(256) void k_agg128(const ushort* __restrict__ feat,
                                                const int* __restrict__ rowptr,
                                                const int* __restrict__ csr_src,
                                                const float* __restrict__ invc,
                                                const float* __restrict__ z,
                                                const float* __restrict__ bias,
                                                ushort* __restrict__ aggb,
                                                float* __restrict__ outf) {
    int gw = (blockIdx.x * 256 + threadIdx.x) >> 6;
    int lane = threadIdx.x & 63;
    if (gw >= NN) return;
    const int grp = lane >> 4, sl = lane & 15;
    const int beg = rowptr[gw], end = rowptr[gw + 1];
    float acc[8] = {};
    int e = beg + grp;
    for (; e + 12 < end; e += 16) {
        int s0 = csr_src[e];
        int s1 = csr_src[e + 4];
        int s2 = csr_src[e + 8];
        int s3 = csr_src[e + 12];
        uint4 u0 = *reinterpret_cast<const uint4*>(&feat[(size_t)s0 * 128 + sl * 8]);
        uint4 u1 = *reinterpret_cast<const uint4*>(&feat[(size_t)s1 * 128 + sl * 8]);
        uint4 u2 = *reinterpret_cast<const uint4*>(&feat[(size_t)s2 * 128 + sl * 8]);
        uint4 u3 = *reinterpret_cast<const uint4*>(&feat[(size_t)s3 * 128 + sl * 8]);
        acc[0] += bf2f((ushort)u0.x) + bf2f((ushort)u1.x) + bf2f((ushort)u2.x) + bf2f((ushort)u3.x);
        acc[1] += bf2f((ushort)(u0.x >> 16)) + bf2f((ushort)(u1.x >> 16)) + bf2f((ushort)(u2.x >> 16)) + bf2f((ushort)(u3.x >> 16));
        acc[2] += bf2f((ushort)u0.y) + bf2f((ushort)u1.y) + bf2f((ushort)u2.y) + bf2f((ushort)u3.y);
        acc[3] += bf2f((ushort)(u0.y >> 16)) + bf2f((ushort)(u1.y >> 16)) + bf2f((ushort)(u2.y >> 16)) + bf2f((ushort)(u3.y >> 16));
        acc[4] += bf2f((ushort)u0.z) + bf2f((ushort)u1.z) + bf2f((ushort)u2.z) + bf2f((ushort)u3.z);
        acc[5] += bf2f((ushort)(u0.z >> 16)) + bf2f((ushort)(u1.z >> 16)) + bf2f((ushort)(u2.z >> 16)) + bf2f((ushort)(u3.z >> 16));
        acc[6] += bf2f((ushort)u0.w) + bf2f((ushort)u1.w) + bf2f((ushort)u2.w) + bf2f((ushort)u3.w);
        acc[7] += bf2f((ushort)(u0.w >> 16)) + bf2f((ushort)(u1.w >> 16)) + bf2f((ushort)(u2.w >> 16)) + bf2f((ushort)(u3.w >> 16));
    }
    for (; e < end; e += 4) {
        int s0 = csr_src[e];
        uint4 u0 = *reinterpret_cast<const uint4*>(&feat[(size_t)s0 * 128 + sl * 8]);
        acc[0] += bf2f((ushort)u0.x); acc[1] += bf2f((ushort)(u0.x >> 16));
        acc[2] += bf2f((ushort)u0.y); acc[3] += bf2f((ushort)(u0.y >> 16));
        acc[4] += bf2f((ushort)u0.z); acc[5] += bf2f((ushort)(u0.z >> 16));
        acc[6] += bf2f((ushort)u0.w); acc[7] += bf2f((ushort)(u0.w >> 16));
    }
    #pragma unroll
    for (int i = 0; i < 8; ++i) {
        acc[i] += __shfl_xor(acc[i], 16);
        acc[i] += __shfl_xor(acc[i], 32);
    }
    if (grp == 0) {
        const float ic = invc[gw];
        if constexpr (FINAL) {
            const float* zp = &z[(size_t)gw * 128 + sl * 8];
            float4 z0 = *reinterpret_cast<const float4*>(zp);
            float4 z1 = *reinterpret_cast<const float4*>(zp + 4);
            float4 b0 = *reinterpret_cast<const float4*>(&bias[sl * 8]);
            float4 b1 = *reinterpret_cast<const float4*>(&bias[sl * 8 + 4]);
            float4 o0, o1;
            o0.x = fmaf(acc[0], ic, z0.x + b0.x);
            o0.y = fmaf(acc[1], ic, z0.y + b0.y);
            o0.z = fmaf(acc[2], ic, z0.z + b0.z);
            o0.w = fmaf(acc[3], ic, z0.w + b0.w);
            o1.x = fmaf(acc[4], ic, z1.x + b1.x);
            o1.y = fmaf(acc[5], ic, z1.y + b1.y);
            o1.z = fmaf(acc[6], ic, z1.z + b1.z);
            o1.w = fmaf(acc[7], ic, z1.w + b1.w);
            float* op = &outf[(size_t)gw * 128 + sl * 8];
            *reinterpret_cast<float4*>(op) = o0;
            *reinterpret_cast<float4*>(op + 4) = o1;
        } else {
            uint4 o;
            o.x = (uint)f2bf(acc[0] * ic) | ((uint)f2bf(acc[1] * ic) << 16);
            o.y = (uint)f2bf(acc[2] * ic) | ((uint)f2bf(acc[3] * ic) << 16);
            o.z = (uint)f2bf(acc[4] * ic) | ((uint)f2bf(acc[5] * ic) << 16);
            o.w = (uint)f2bf(acc[6] * ic) | ((uint)f2bf(acc[7] * ic) << 16);
            *reinterpret_cast<uint4*>(&aggb[(size_t)gw * 128 + sl * 8]) = o;
        }
    }
}

// ---- MFMA GEMM: out = [A1 | A2] @ Wt^T (+bias) ----
// Block = 128 rows x 64 cols, 4 waves (wave tile 32x64).
// B slice (64 cols x KT) preloaded to LDS ONCE (pad stride 264 -> 2-way-free),
// single barrier; K-loop is barrier-free: A fragments load DIRECTLY from global
// (full 64B-line coalescing), fully unrolled -> deep MLP, waves slip freely.
template <int K1, int K2, int NC, bool STATS, bool BN1, int OUTMODE>
__global__ __launch_bounds__(256, 4) void k_mm(const ushort* __restrict__ A1,
                                               const ushort* __restrict__ A2,
                                               const ushort* __restrict__ Wt,
                                               const float* __restrict__ bias,
                                               const float* __restrict__ sc,
                                               const float* __restrict__ sh,
                                               float* __restrict__ bnsums,
                                               ushort* __restrict__ outb,
                                               float* __restrict__ outf) {
    constexpr int KT = K1 + K2;
    constexpr int NIT = KT / 32;
    constexpr int BSTR = 264;            // LDS col stride (ushorts): 2-way-free
    __shared__ ushort Bs[64 * BSTR];
    __shared__ float sred[4][4][16][2];
    const int t = threadIdx.x;
    const int lane = t & 63, wid = t >> 6;       // wid = wave row-group
    const int r0 = blockIdx.x * 128, c0 = blockIdx.y * 64;
    const int lr = lane & 15, lg = lane >> 4;
    const int wrow = r0 + wid * 32;

    // B preload: 64 cols x KT k = 64*KT/8 slots of bf16x8; coalesced (32 slots/col)
    #pragma unroll
    for (int i = 0; i < 64 * KT / 8 / 256; ++i) {
        int idx = i * 256 + t;
        int col = idx / (KT / 8);
        int slot = idx % (KT / 8);
        *reinterpret_cast<bf16x8*>(&Bs[col * BSTR + slot * 8]) =
            *reinterpret_cast<const bf16x8*>(&Wt[(size_t)(c0 + col) * KT + slot * 8]);
    }
    __syncthreads();

    f32x4 acc[2][4] = {};
    #pragma unroll
    for (int it = 0; it < NIT; ++it) {
        const int kt = it * 32;
        const ushort* __restrict__ Ap = (kt < K1) ? A1 : A2;
        const int AK = (kt < K1) ? K1 : K2;
        const int ak = (kt < K1) ? kt : kt - K1;
        bf16x8 af[2];
        #pragma unroll
        for (int mi = 0; mi < 2; ++mi) {
            af[mi] = *reinterpret_cast<const bf16x8*>(
                &Ap[(size_t)(wrow + mi * 16 + lr) * AK + ak + lg * 8]);
            if constexpr (BN1) {   // only used with K2==0 (ak == kt)
                const int cb = kt + lg * 8;
                float4 s0 = *reinterpret_cast<const float4*>(&sc[cb]);
                float4 s1 = *reinterpret_cast<const float4*>(&sc[cb + 4]);
                float4 h0 = *reinterpret_cast<const float4*>(&sh[cb]);
                float4 h1 = *reinterpret_cast<const float4*>(&sh[cb + 4]);
                float fsv[8] = {s0.x, s0.y, s0.z, s0.w, s1.x, s1.y, s1.z, s1.w};
                float fhv[8] = {h0.x, h0.y, h0.z, h0.w, h1.x, h1.y, h1.z, h1.w};
                #pragma unroll
                for (int j = 0; j < 8; ++j) {
                    float f = bf2f((ushort)af[mi][j]);
                    f = fmaxf(fmaf(f, fsv[j], fhv[j]), 0.f);
                    af[mi][j] = (short)f2bf(f);
                }
            }
        }
        bf16x8 bf[4];
        #pragma unroll
        for (int nj = 0; nj < 4; ++nj)
            bf[nj] = *reinterpret_cast<bf16x8*>(&Bs[(nj * 16 + lr) * BSTR + kt + lg * 8]);
        #pragma unroll
        for (int mi = 0; mi < 2; ++mi)
            #pragma unroll
            for (int nj = 0; nj < 4; ++nj)
                acc[mi][nj] = __builtin_amdgcn_mfma_f32_16x16x32_bf16(af[mi], bf[nj], acc[mi][nj], 0, 0, 0);
    }

    float ssum[4] = {}, s2sum[4] = {};
    #pragma unroll
    for (int nj = 0; nj < 4; ++nj) {
        const int col = c0 + nj * 16 + lr;
        float bv = 0.f;
        if constexpr (OUTMODE == 0) bv = bias[col];
        #pragma unroll
        for (int mi = 0; mi < 2; ++mi) {
            const int rbase = wrow + mi * 16;
            if (rbase + 16 > NN) continue;
            #pragma unroll
            for (int reg = 0; reg < 4; ++reg) {
                const int row = rbase + lg * 4 + reg;
                float d = acc[mi][nj][reg] + bv;
                if constexpr (STATS) { ssum[nj] += d; s2sum[nj] += d * d; }
                if constexpr (OUTMODE == 0) {
                    outb[(size_t)row * NC + col] = f2bf(d);
                } else {
                    if (col < 128) outb[(size_t)row * 128 + col] = f2bf(d);
                    else outf[(size_t)row * 128 + (col - 128)] = d;
                }
            }
        }
    }
    if constexpr (STATS) {
        #pragma unroll
        for (int nj = 0; nj < 4; ++nj) {
            ssum[nj] += __shfl_xor(ssum[nj], 16); ssum[nj] += __shfl_xor(ssum[nj], 32);
            s2sum[nj] += __shfl_xor(s2sum[nj], 16); s2sum[nj] += __shfl_xor(s2sum[nj], 32);
        }
        if (lane < 16) {
            #pragma unroll
            for (int nj = 0; nj < 4; ++nj) {
                sred[wid][nj][lane][0] = ssum[nj];
                sred[wid][nj][lane][1] = s2sum[nj];
            }
        }
        __syncthreads();
        if (wid == 0 && lane < 16) {
            #pragma unroll
            for (int nj = 0; nj < 4; ++nj) {
                const int col = c0 + nj * 16 + lane;
                float s = sred[0][nj][lane][0] + sred[1][nj][lane][0] + sred[2][nj][lane][0] + sred[3][nj][lane][0];
                float s2 = sred[0][nj][lane][1] + sred[1][nj][lane][1] + sred[2][nj][lane][1] + sred[3][nj][lane][1];
                atomAddF(&bnsums[col], s);
                atomAddF(&bnsums[256 + col], s2);
            }
        }
    }
}

// ---- BN finalize ----
__global__ void k_bnfin(const float* __restrict__ sums, const float* __restrict__ gamma,
                        const float* __restrict__ beta, float* __restrict__ sc,
                        float* __restrict__ sh) {
    int c = threadIdx.x;
    float mu = sums[c] * (1.0f / NN);
    float var = sums[256 + c] * (1.0f / NN) - mu * mu;
    float s = gamma[c] * rsqrtf(var + BN_EPS);
    sc[c] = s;
    sh[c] = beta[c] - mu * s;
}

extern "C" void kernel_launch(void* const* d_in, const int* in_sizes, int n_in,
                              void* d_out, int out_size, void* d_ws, size_t ws_size,
                              hipStream_t stream) {
    const float* x    = (const float*)d_in[0];
    const int*   ei   = (const int*)d_in[1];
    const float* W1l  = (const float*)d_in[2];
    const float* b1l  = (const float*)d_in[3];
    const float* W1r  = (const float*)d_in[4];
    const float* gam1 = (const float*)d_in[5];
    const float* bet1 = (const float*)d_in[6];
    const float* W2l  = (const float*)d_in[7];
    const float* b2l  = (const float*)d_in[8];
    const float* W2r  = (const float*)d_in[9];
    float* out = (float*)d_out;

    char* p = (char*)d_ws;
    ushort* xb   = (ushort*)p; p += (size_t)MPAD * 128 * 2;
    ushort* hb   = (ushort*)p; p += (size_t)MPAD * 256 * 2;
    ushort* aggb = (ushort*)p; p += (size_t)MPAD * 128 * 2;
    ushort* y2b  = (ushort*)p; p += (size_t)MPAD * 128 * 2;
    float*  zf   = (float*)p;  p += (size_t)MPAD * 128 * 4;
    ushort* Wt1  = (ushort*)p; p += 256 * 256 * 2;
    ushort* Wt2  = (ushort*)p; p += 256 * 256 * 2;
    int*   cnt    = (int*)p;   p += (size_t)NPAD * 4;
    float* bnsums = (float*)p; p += 512 * 4;
    float* bnsc   = (float*)p; p += 256 * 4;
    float* bnsh   = (float*)p; p += 256 * 4;
    float* invc   = (float*)p; p += (size_t)NPAD * 4;
    int*   rowptr = (int*)p;   p += (size_t)(NPAD + 4) * 4;
    int*   csr_src= (int*)p;   p += (size_t)NE * 4;
    int2*  seg    = (int2*)p;  p += (size_t)NE * 8;
    int*   cnt2   = (int*)p;   p += (size_t)NSEG * NBKT * 4;
    int*   boff2  = (int*)p;   p += (size_t)NSEG * NBKT * 4;
    int*   bsum   = (int*)p;   p += 64 * 4;
    int*   locpre = (int*)aggb;  // overlay: consumed by k_scanC before aggb written

    hipMemsetAsync(cnt, 0, (size_t)NPAD * 4 + 4096, stream);

    // CSR build: partition-sort (fused degree) -> scan -> ranked fill
    k_part<<<NSEG, 256, 0, stream>>>(ei, cnt, seg, cnt2, boff2);
    k_scanA<<<NPAD / 1024, 256, 0, stream>>>(cnt, locpre, bsum);
    k_scanC<<<NPAD / 1024, 256, 0, stream>>>(cnt, locpre, bsum, rowptr, invc);
    k_rank<<<NBKT, 1024, 0, stream>>>(seg, cnt2, boff2, rowptr, csr_src);

    // bf16 precompute (castx + weight transpose fused)
    k_prep<<<3637, 256, 0, stream>>>(x, xb, W1l, W1r, W2l, W2r, Wt1, Wt2);

    // Layer 1: agg(x) -> GEMM [agg|x]@Wt1 (+bias, BN stats) -> bnfin
    k_agg128<false><<<12500, 256, 0, stream>>>(xb, rowptr, csr_src, invc, nullptr, nullptr, aggb, nullptr);
    k_mm<128, 128, 256, true, false, 0><<<dim3(391, 4), 256, 0, stream>>>(
        aggb, xb, Wt1, b1l, nullptr, nullptr, bnsums, hb, nullptr);
    k_bnfin<<<1, 256, 0, stream>>>(bnsums, gam1, bet1, bnsc, bnsh);

    // Layer 2 (swapped): [y2|z] = relu(bn(h)) @ [W2l|W2r]; out = mean(y2[src]) + z + b
    k_mm<256, 0, 256, false, true, 1><<<dim3(391, 4), 256, 0, stream>>>(
        hb, nullptr, Wt2, nullptr, bnsc, bnsh, nullptr, y2b, zf);
    k_agg128<true><<<12500, 256, 0, stream>>>(y2b, rowptr, csr_src, invc, zf, b2l, nullptr, out);
}

// Round 15
// 213.792 us; speedup vs baseline: 1.1833x; 1.0667x over previous
//
#include <hip/hip_runtime.h>

#define NN 50000
#define NPAD 50176   // NN rounded up to 49*1024 (scan int4 loads)
#define MPAD 50048   // 782*64 (GEMM row tiles)
#define NE 800000
#define BN_EPS 1e-5f

#define NSEG 782     // edge chunks of 1024
#define NBKT 49      // dst buckets of 1024 nodes

typedef __attribute__((ext_vector_type(8))) short bf16x8;
typedef __attribute__((ext_vector_type(4))) float f32x4;

__device__ __forceinline__ void atomAddF(float* p, float v) { unsafeAtomicAdd(p, v); }

__device__ __forceinline__ float bf2f(ushort u) {
    union { uint i; float f; } v; v.i = ((uint)u) << 16; return v.f;
}
__device__ __forceinline__ ushort f2bf(float f) {
    union { uint i; float f; } v; v.f = f;
    uint u = v.i;
    return (ushort)((u + 0x7FFFu + ((u >> 16) & 1u)) >> 16);  // RNE
}

// ---- zero cnt + bn scratch (replaces 40us runtime fillBuffer) ----
__global__ __launch_bounds__(256) void k_zero(int4* __restrict__ dst) {
    // (NPAD + 1024) ints = 12800 int4 slots; grid 50 x 256
    dst[blockIdx.x * 256 + threadIdx.x] = make_int4(0, 0, 0, 0);
}

// ---- fill phase 1: per-block counting sort of 1024 edges by dst-bucket ----
__global__ __launch_bounds__(256) void k_part(const int* __restrict__ ei,
                                              int* __restrict__ cnt,
                                              int2* __restrict__ seg,
                                              int* __restrict__ cnt2,
                                              int* __restrict__ boff2) {
    __shared__ int lcnt[NBKT];
    __shared__ int lboff[NBKT];
    __shared__ int2 lbuf[1024];
    const int b = blockIdx.x, t = threadIdx.x;
    if (t < NBKT) lcnt[t] = 0;
    __syncthreads();
    int src[4], dst[4], rk[4], bkt[4];
    const int e0 = b * 1024;
    #pragma unroll
    for (int j = 0; j < 4; ++j) {
        int e = e0 + t + j * 256;
        if (e < NE) {
            src[j] = ei[e];
            dst[j] = ei[NE + e];
            bkt[j] = dst[j] >> 10;
            rk[j] = atomicAdd(&lcnt[bkt[j]], 1);
            atomicAdd(&cnt[dst[j]], 1);          // fused degree count
        } else rk[j] = -1;
    }
    __syncthreads();
    if (t < 64) {  // wave 0: exclusive scan of 49 bucket counts
        int v = (t < NBKT) ? lcnt[t] : 0;
        int x = v;
        #pragma unroll
        for (int off = 1; off < 64; off <<= 1) {
            int y = __shfl_up(x, off);
            if (t >= off) x += y;
        }
        if (t < NBKT) lboff[t] = x - v;
    }
    __syncthreads();
    #pragma unroll
    for (int j = 0; j < 4; ++j)
        if (rk[j] >= 0) lbuf[lboff[bkt[j]] + rk[j]] = make_int2(src[j], dst[j]);
    __syncthreads();
    const int total = lboff[NBKT - 1] + lcnt[NBKT - 1];
    for (int i = t; i < total; i += 256) seg[e0 + i] = lbuf[i];   // coalesced
    if (t < NBKT) { cnt2[b * NBKT + t] = lcnt[t]; boff2[b * NBKT + t] = lboff[t]; }
}

// ---- fill phase 2: one block per bucket; LDS ranks; writes confined to bucket window ----
__global__ __launch_bounds__(1024) void k_rank(const int2* __restrict__ seg,
                                               const int* __restrict__ cnt2,
                                               const int* __restrict__ boff2,
                                               const int* __restrict__ rowptr,
                                               int* __restrict__ csr_src) {
    __shared__ int lrk[1024];
    const int k = blockIdx.x, t = threadIdx.x;
    lrk[t] = 0;
    __syncthreads();
    const int node0 = k << 10;
    const int g = t >> 3, l = t & 7;   // 128 groups x 8 lanes
    for (int b = g; b < NSEG; b += 128) {
        const int n = cnt2[b * NBKT + k];
        const int base = b * 1024 + boff2[b * NBKT + k];
        for (int i = l; i < n; i += 8) {
            int2 e = seg[base + i];
            int rank = atomicAdd(&lrk[e.y - node0], 1);
            csr_src[rowptr[e.y] + rank] = e.x;
        }
    }
}

// ---- CSR scan phase A ----
__global__ __launch_bounds__(256) void k_scanA(const int* __restrict__ cnt,
                                               int* __restrict__ locpre, int* __restrict__ bsum) {
    const int b = blockIdx.x, t = threadIdx.x;
    const int base = b * 1024 + t * 4;
    int4 v = *reinterpret_cast<const int4*>(&cnt[base]);
    int s = v.x + v.y + v.z + v.w;
    __shared__ int sm[256];
    sm[t] = s;
    __syncthreads();
    for (int off = 1; off < 256; off <<= 1) {
        int y = (t >= off) ? sm[t - off] : 0;
        __syncthreads();
        sm[t] += y;
        __syncthreads();
    }
    int excl = sm[t] - s;
    locpre[base + 0] = excl;
    locpre[base + 1] = excl + v.x;
    locpre[base + 2] = excl + v.x + v.y;
    locpre[base + 3] = excl + v.x + v.y + v.z;
    if (t == 255) bsum[b] = sm[255];
}

// ---- CSR scan phase C ----
__global__ __launch_bounds__(256) void k_scanC(const int* __restrict__ cnt,
                                               const int* __restrict__ locpre,
                                               const int* __restrict__ bsum,
                                               int* __restrict__ rowptr,
                                               float* __restrict__ invc) {
    __shared__ int sm[64];
    const int b = blockIdx.x, t = threadIdx.x;
    const int nb = NPAD / 1024;  // 49
    if (t < nb) sm[t] = bsum[t];
    __syncthreads();
    int off = 0;
    for (int j = 0; j < b; ++j) off += sm[j];
    const int base = b * 1024 + t * 4;
    #pragma unroll
    for (int k = 0; k < 4; ++k) {
        int i = base + k;
        if (i < NN) {
            rowptr[i] = locpre[i] + off;
            invc[i] = 1.0f / fmaxf((float)cnt[i], 1.0f);
        }
    }
    if (b == 0 && t == 0) rowptr[NN] = NE;
}

// ---- prep: cast x -> bf16 + transposed bf16 weights ----
__global__ __launch_bounds__(256) void k_prep(const float* __restrict__ x, ushort* __restrict__ xb,
                                              const float* __restrict__ W1l, const float* __restrict__ W1r,
                                              const float* __restrict__ W2l, const float* __restrict__ W2r,
                                              ushort* __restrict__ Wt1, ushort* __restrict__ Wt2) {
    if (blockIdx.x < 3125) {
        unsigned g = blockIdx.x * 256u + threadIdx.x;  // < 800000 exactly
        const float4* p = reinterpret_cast<const float4*>(x) + (size_t)g * 2;
        float4 a = p[0], b = p[1];
        uint4 w;
        w.x = (uint)f2bf(a.x) | ((uint)f2bf(a.y) << 16);
        w.y = (uint)f2bf(a.z) | ((uint)f2bf(a.w) << 16);
        w.z = (uint)f2bf(b.x) | ((uint)f2bf(b.y) << 16);
        w.w = (uint)f2bf(b.z) | ((uint)f2bf(b.w) << 16);
        *reinterpret_cast<uint4*>(&xb[(size_t)g * 8]) = w;
    } else {
        int g = (blockIdx.x - 3125) * 256 + threadIdx.x;  // < 131072 exactly
        if (g < 65536) {
            int n = g >> 8, k = g & 255;
            float v = (k < 128) ? W1l[k * 256 + n] : W1r[(k - 128) * 256 + n];
            Wt1[n * 256 + k] = f2bf(v);
        } else {
            int g2 = g - 65536;
            int n = g2 >> 8, k = g2 & 255;
            float v = (n < 128) ? W2l[k * 128 + n] : W2r[k * 128 + (n - 128)];
            Wt2[n * 256 + k] = f2bf(v);
        }
    }
}

// ---- gather-aggregate over 128-ch bf16 rows, 4-way edge-parallel, 4x unrolled ----
template <bool FINAL>
__global__ __launch_bounds__(256) void k_agg128(const ushort* __restrict__ feat,
                                                const int* __restrict__ rowptr,
                                                const int* __restrict__ csr_src,
                                                const float* __restrict__ invc,
                                                const float* __restrict__ z,
                                                const float* __restrict__ bias,
                                                ushort* __restrict__ aggb,
                                                float* __restrict__ outf) {
    int gw = (blockIdx.x * 256 + threadIdx.x) >> 6;
    int lane = threadIdx.x & 63;
    if (gw >= NN) return;
    const int grp = lane >> 4, sl = lane & 15;
    const int beg = rowptr[gw], end = rowptr[gw + 1];
    float acc[8] = {};
    int e = beg + grp;
    for (; e + 12 < end; e += 16) {
        int s0 = csr_src[e];
        int s1 = csr_src[e + 4];
        int s2 = csr_src[e + 8];
        int s3 = csr_src[e + 12];
        uint4 u0 = *reinterpret_cast<const uint4*>(&feat[(size_t)s0 * 128 + sl * 8]);
        uint4 u1 = *reinterpret_cast<const uint4*>(&feat[(size_t)s1 * 128 + sl * 8]);
        uint4 u2 = *reinterpret_cast<const uint4*>(&feat[(size_t)s2 * 128 + sl * 8]);
        uint4 u3 = *reinterpret_cast<const uint4*>(&feat[(size_t)s3 * 128 + sl * 8]);
        acc[0] += bf2f((ushort)u0.x) + bf2f((ushort)u1.x) + bf2f((ushort)u2.x) + bf2f((ushort)u3.x);
        acc[1] += bf2f((ushort)(u0.x >> 16)) + bf2f((ushort)(u1.x >> 16)) + bf2f((ushort)(u2.x >> 16)) + bf2f((ushort)(u3.x >> 16));
        acc[2] += bf2f((ushort)u0.y) + bf2f((ushort)u1.y) + bf2f((ushort)u2.y) + bf2f((ushort)u3.y);
        acc[3] += bf2f((ushort)(u0.y >> 16)) + bf2f((ushort)(u1.y >> 16)) + bf2f((ushort)(u2.y >> 16)) + bf2f((ushort)(u3.y >> 16));
        acc[4] += bf2f((ushort)u0.z) + bf2f((ushort)u1.z) + bf2f((ushort)u2.z) + bf2f((ushort)u3.z);
        acc[5] += bf2f((ushort)(u0.z >> 16)) + bf2f((ushort)(u1.z >> 16)) + bf2f((ushort)(u2.z >> 16)) + bf2f((ushort)(u3.z >> 16));
        acc[6] += bf2f((ushort)u0.w) + bf2f((ushort)u1.w) + bf2f((ushort)u2.w) + bf2f((ushort)u3.w);
        acc[7] += bf2f((ushort)(u0.w >> 16)) + bf2f((ushort)(u1.w >> 16)) + bf2f((ushort)(u2.w >> 16)) + bf2f((ushort)(u3.w >> 16));
    }
    for (; e < end; e += 4) {
        int s0 = csr_src[e];
        uint4 u0 = *reinterpret_cast<const uint4*>(&feat[(size_t)s0 * 128 + sl * 8]);
        acc[0] += bf2f((ushort)u0.x); acc[1] += bf2f((ushort)(u0.x >> 16));
        acc[2] += bf2f((ushort)u0.y); acc[3] += bf2f((ushort)(u0.y >> 16));
        acc[4] += bf2f((ushort)u0.z); acc[5] += bf2f((ushort)(u0.z >> 16));
        acc[6] += bf2f((ushort)u0.w); acc[7] += bf2f((ushort)(u0.w >> 16));
    }
    #pragma unroll
    for (int i = 0; i < 8; ++i) {
        acc[i] += __shfl_xor(acc[i], 16);
        acc[i] += __shfl_xor(acc[i], 32);
    }
    if (grp == 0) {
        const float ic = invc[gw];
        if constexpr (FINAL) {
            const float* zp = &z[(size_t)gw * 128 + sl * 8];
            float4 z0 = *reinterpret_cast<const float4*>(zp);
            float4 z1 = *reinterpret_cast<const float4*>(zp + 4);
            float4 b0 = *reinterpret_cast<const float4*>(&bias[sl * 8]);
            float4 b1 = *reinterpret_cast<const float4*>(&bias[sl * 8 + 4]);
            float4 o0, o1;
            o0.x = fmaf(acc[0], ic, z0.x + b0.x);
            o0.y = fmaf(acc[1], ic, z0.y + b0.y);
            o0.z = fmaf(acc[2], ic, z0.z + b0.z);
            o0.w = fmaf(acc[3], ic, z0.w + b0.w);
            o1.x = fmaf(acc[4], ic, z1.x + b1.x);
            o1.y = fmaf(acc[5], ic, z1.y + b1.y);
            o1.z = fmaf(acc[6], ic, z1.z + b1.z);
            o1.w = fmaf(acc[7], ic, z1.w + b1.w);
            float* op = &outf[(size_t)gw * 128 + sl * 8];
            *reinterpret_cast<float4*>(op) = o0;
            *reinterpret_cast<float4*>(op + 4) = o1;
        } else {
            uint4 o;
            o.x = (uint)f2bf(acc[0] * ic) | ((uint)f2bf(acc[1] * ic) << 16);
            o.y = (uint)f2bf(acc[2] * ic) | ((uint)f2bf(acc[3] * ic) << 16);
            o.z = (uint)f2bf(acc[4] * ic) | ((uint)f2bf(acc[5] * ic) << 16);
            o.w = (uint)f2bf(acc[6] * ic) | ((uint)f2bf(acc[7] * ic) << 16);
            *reinterpret_cast<uint4*>(&aggb[(size_t)gw * 128 + sl * 8]) = o;
        }
    }
}

// ---- MFMA GEMM: out = [A1 | A2] @ Wt^T (+bias) ----
// 1D grid 1564 = 391 row-tiles x 4 col-tiles, XCD-chunked bijective swizzle:
// the 4 col-blocks sharing an A row-panel map to the SAME XCD -> A L2-resident.
// B slice preloaded to LDS once; K-loop barrier-free, A direct from global.
template <int K1, int K2, int NC, bool STATS, bool BN1, int OUTMODE>
__global__ __launch_bounds__(256, 4) void k_mm(const ushort* __restrict__ A1,
                                               const ushort* __restrict__ A2,
                                               const ushort* __restrict__ Wt,
                                               const float* __restrict__ bias,
                                               const float* __restrict__ sc,
                                               const float* __restrict__ sh,
                                               float* __restrict__ bnsums,
                                               ushort* __restrict__ outb,
                                               float* __restrict__ outf) {
    constexpr int KT = K1 + K2;
    constexpr int NIT = KT / 32;
    constexpr int BSTR = 264;            // LDS col stride (ushorts)
    constexpr int NWG = 1564, Q = NWG / 8, R = NWG % 8;   // 195, 4
    __shared__ ushort Bs[64 * BSTR];
    __shared__ float sred[4][4][16][2];
    const int t = threadIdx.x;
    const int lane = t & 63, wid = t >> 6;       // wid = wave row-group
    // XCD-chunked swizzle (bijective; dispatch d -> XCD d%8 assumption)
    const int bid = blockIdx.x;
    const int xcd = bid & 7, idx = bid >> 3;
    const int logical = (xcd < R ? xcd * (Q + 1) : R * (Q + 1) + (xcd - R) * Q) + idx;
    const int r0 = (logical >> 2) * 128, c0 = (logical & 3) * 64;
    const int lr = lane & 15, lg = lane >> 4;
    const int wrow = r0 + wid * 32;

    // B preload: 64 cols x KT k; coalesced
    #pragma unroll
    for (int i = 0; i < 64 * KT / 8 / 256; ++i) {
        int idx2 = i * 256 + t;
        int col = idx2 / (KT / 8);
        int slot = idx2 % (KT / 8);
        *reinterpret_cast<bf16x8*>(&Bs[col * BSTR + slot * 8]) =
            *reinterpret_cast<const bf16x8*>(&Wt[(size_t)(c0 + col) * KT + slot * 8]);
    }
    __syncthreads();

    f32x4 acc[2][4] = {};
    #pragma unroll
    for (int it = 0; it < NIT; ++it) {
        const int kt = it * 32;
        const ushort* __restrict__ Ap = (kt < K1) ? A1 : A2;
        const int AK = (kt < K1) ? K1 : K2;
        const int ak = (kt < K1) ? kt : kt - K1;
        bf16x8 af[2];
        #pragma unroll
        for (int mi = 0; mi < 2; ++mi) {
            af[mi] = *reinterpret_cast<const bf16x8*>(
                &Ap[(size_t)(wrow + mi * 16 + lr) * AK + ak + lg * 8]);
            if constexpr (BN1) {   // only used with K2==0 (ak == kt)
                const int cb = kt + lg * 8;
                float4 s0 = *reinterpret_cast<const float4*>(&sc[cb]);
                float4 s1 = *reinterpret_cast<const float4*>(&sc[cb + 4]);
                float4 h0 = *reinterpret_cast<const float4*>(&sh[cb]);
                float4 h1 = *reinterpret_cast<const float4*>(&sh[cb + 4]);
                float fsv[8] = {s0.x, s0.y, s0.z, s0.w, s1.x, s1.y, s1.z, s1.w};
                float fhv[8] = {h0.x, h0.y, h0.z, h0.w, h1.x, h1.y, h1.z, h1.w};
                #pragma unroll
                for (int j = 0; j < 8; ++j) {
                    float f = bf2f((ushort)af[mi][j]);
                    f = fmaxf(fmaf(f, fsv[j], fhv[j]), 0.f);
                    af[mi][j] = (short)f2bf(f);
                }
            }
        }
        bf16x8 bf[4];
        #pragma unroll
        for (int nj = 0; nj < 4; ++nj)
            bf[nj] = *reinterpret_cast<bf16x8*>(&Bs[(nj * 16 + lr) * BSTR + kt + lg * 8]);
        #pragma unroll
        for (int mi = 0; mi < 2; ++mi)
            #pragma unroll
            for (int nj = 0; nj < 4; ++nj)
                acc[mi][nj] = __builtin_amdgcn_mfma_f32_16x16x32_bf16(af[mi], bf[nj], acc[mi][nj], 0, 0, 0);
    }

    float ssum[4] = {}, s2sum[4] = {};
    #pragma unroll
    for (int nj = 0; nj < 4; ++nj) {
        const int col = c0 + nj * 16 + lr;
        float bv = 0.f;
        if constexpr (OUTMODE == 0) bv = bias[col];
        #pragma unroll
        for (int mi = 0; mi < 2; ++mi) {
            const int rbase = wrow + mi * 16;
            if (rbase + 16 > NN) continue;
            #pragma unroll
            for (int reg = 0; reg < 4; ++reg) {
                const int row = rbase + lg * 4 + reg;
                float d = acc[mi][nj][reg] + bv;
                if constexpr (STATS) { ssum[nj] += d; s2sum[nj] += d * d; }
                if constexpr (OUTMODE == 0) {
                    outb[(size_t)row * NC + col] = f2bf(d);
                } else {
                    if (col < 128) outb[(size_t)row * 128 + col] = f2bf(d);
                    else outf[(size_t)row * 128 + (col - 128)] = d;
                }
            }
        }
    }
    if constexpr (STATS) {
        #pragma unroll
        for (int nj = 0; nj < 4; ++nj) {
            ssum[nj] += __shfl_xor(ssum[nj], 16); ssum[nj] += __shfl_xor(ssum[nj], 32);
            s2sum[nj] += __shfl_xor(s2sum[nj], 16); s2sum[nj] += __shfl_xor(s2sum[nj], 32);
        }
        if (lane < 16) {
            #pragma unroll
            for (int nj = 0; nj < 4; ++nj) {
                sred[wid][nj][lane][0] = ssum[nj];
                sred[wid][nj][lane][1] = s2sum[nj];
            }
        }
        __syncthreads();
        if (wid == 0 && lane < 16) {
            #pragma unroll
            for (int nj = 0; nj < 4; ++nj) {
                const int col = c0 + nj * 16 + lane;
                float s = sred[0][nj][lane][0] + sred[1][nj][lane][0] + sred[2][nj][lane][0] + sred[3][nj][lane][0];
                float s2 = sred[0][nj][lane][1] + sred[1][nj][lane][1] + sred[2][nj][lane][1] + sred[3][nj][lane][1];
                atomAddF(&bnsums[col], s);
                atomAddF(&bnsums[256 + col], s2);
            }
        }
    }
}

// ---- BN finalize ----
__global__ void k_bnfin(const float* __restrict__ sums, const float* __restrict__ gamma,
                        const float* __restrict__ beta, float* __restrict__ sc,
                        float* __restrict__ sh) {
    int c = threadIdx.x;
    float mu = sums[c] * (1.0f / NN);
    float var = sums[256 + c] * (1.0f / NN) - mu * mu;
    float s = gamma[c] * rsqrtf(var + BN_EPS);
    sc[c] = s;
    sh[c] = beta[c] - mu * s;
}

extern "C" void kernel_launch(void* const* d_in, const int* in_sizes, int n_in,
                              void* d_out, int out_size, void* d_ws, size_t ws_size,
                              hipStream_t stream) {
    const float* x    = (const float*)d_in[0];
    const int*   ei   = (const int*)d_in[1];
    const float* W1l  = (const float*)d_in[2];
    const float* b1l  = (const float*)d_in[3];
    const float* W1r  = (const float*)d_in[4];
    const float* gam1 = (const float*)d_in[5];
    const float* bet1 = (const float*)d_in[6];
    const float* W2l  = (const float*)d_in[7];
    const float* b2l  = (const float*)d_in[8];
    const float* W2r  = (const float*)d_in[9];
    float* out = (float*)d_out;

    char* p = (char*)d_ws;
    ushort* xb   = (ushort*)p; p += (size_t)MPAD * 128 * 2;
    ushort* hb   = (ushort*)p; p += (size_t)MPAD * 256 * 2;
    ushort* aggb = (ushort*)p; p += (size_t)MPAD * 128 * 2;
    ushort* y2b  = (ushort*)p; p += (size_t)MPAD * 128 * 2;
    float*  zf   = (float*)p;  p += (size_t)MPAD * 128 * 4;
    ushort* Wt1  = (ushort*)p; p += 256 * 256 * 2;
    ushort* Wt2  = (ushort*)p; p += 256 * 256 * 2;
    int*   cnt    = (int*)p;   p += (size_t)NPAD * 4;
    float* bnsums = (float*)p; p += 512 * 4;
    float* bnsc   = (float*)p; p += 256 * 4;
    float* bnsh   = (float*)p; p += 256 * 4;
    float* invc   = (float*)p; p += (size_t)NPAD * 4;
    int*   rowptr = (int*)p;   p += (size_t)(NPAD + 4) * 4;
    int*   csr_src= (int*)p;   p += (size_t)NE * 4;
    int2*  seg    = (int2*)p;  p += (size_t)NE * 8;
    int*   cnt2   = (int*)p;   p += (size_t)NSEG * NBKT * 4;
    int*   boff2  = (int*)p;   p += (size_t)NSEG * NBKT * 4;
    int*   bsum   = (int*)p;   p += 64 * 4;
    int*   locpre = (int*)aggb;  // overlay: consumed by k_scanC before aggb written

    // zero cnt + bn scratch with our own kernel (runtime fill kernel took 40us)
    k_zero<<<(NPAD + 1024) / 4 / 256, 256, 0, stream>>>((int4*)cnt);

    // CSR build: partition-sort (fused degree) -> scan -> ranked fill
    k_part<<<NSEG, 256, 0, stream>>>(ei, cnt, seg, cnt2, boff2);
    k_scanA<<<NPAD / 1024, 256, 0, stream>>>(cnt, locpre, bsum);
    k_scanC<<<NPAD / 1024, 256, 0, stream>>>(cnt, locpre, bsum, rowptr, invc);
    k_rank<<<NBKT, 1024, 0, stream>>>(seg, cnt2, boff2, rowptr, csr_src);

    // bf16 precompute (castx + weight transpose fused)
    k_prep<<<3637, 256, 0, stream>>>(x, xb, W1l, W1r, W2l, W2r, Wt1, Wt2);

    // Layer 1: agg(x) -> GEMM [agg|x]@Wt1 (+bias, BN stats) -> bnfin
    k_agg128<false><<<12500, 256, 0, stream>>>(xb, rowptr, csr_src, invc, nullptr, nullptr, aggb, nullptr);
    k_mm<128, 128, 256, true, false, 0><<<1564, 256, 0, stream>>>(
        aggb, xb, Wt1, b1l, nullptr, nullptr, bnsums, hb, nullptr);
    k_bnfin<<<1, 256, 0, stream>>>(bnsums, gam1, bet1, bnsc, bnsh);

    // Layer 2 (swapped): [y2|z] = relu(bn(h)) @ [W2l|W2r]; out = mean(y2[src]) + z + b
    k_mm<256, 0, 256, false, true, 1><<<1564, 256, 0, stream>>>(
        hb, nullptr, Wt2, nullptr, bnsc, bnsh, nullptr, y2b, zf);
    k_agg128<true><<<12500, 256, 0, stream>>>(y2b, rowptr, csr_src, invc, zf, b2l, nullptr, out);
}

// Round 16
// 184.596 us; speedup vs baseline: 1.3704x; 1.1582x over previous
//
#include <hip/hip_runtime.h>

#define NN 50000
#define NPAD 50176   // NN rounded up to 49*1024 (scan int4 loads)
#define MPAD 50048   // 782*64 (GEMM row tiles)
#define NE 800000
#define BN_EPS 1e-5f

#define NSEG 782     // edge chunks of 1024
#define NBKT 49      // dst buckets of 1024 nodes

typedef __attribute__((ext_vector_type(8))) short bf16x8;
typedef __attribute__((ext_vector_type(4))) float f32x4;

__device__ __forceinline__ void atomAddF(float* p, float v) { unsafeAtomicAdd(p, v); }

__device__ __forceinline__ float bf2f(ushort u) {
    union { uint i; float f; } v; v.i = ((uint)u) << 16; return v.f;
}
__device__ __forceinline__ ushort f2bf(float f) {
    union { uint i; float f; } v; v.f = f;
    uint u = v.i;
    return (ushort)((u + 0x7FFFu + ((u >> 16) & 1u)) >> 16);  // RNE
}

// ---- zero bnsums (512 floats + pad) ----
__global__ __launch_bounds__(256) void k_zero(int4* __restrict__ dst) {
    if (threadIdx.x < 128) dst[threadIdx.x] = make_int4(0, 0, 0, 0);
}

// ---- fill phase 1: per-block counting sort of 1024 edges by dst-bucket ----
// NO global atomics: degree is derived later (k_cnt) from the partitioned runs.
__global__ __launch_bounds__(256) void k_part(const int* __restrict__ ei,
                                              int2* __restrict__ seg,
                                              int* __restrict__ cnt2,
                                              int* __restrict__ boff2) {
    __shared__ int lcnt[NBKT];
    __shared__ int lboff[NBKT];
    __shared__ int2 lbuf[1024];
    const int b = blockIdx.x, t = threadIdx.x;
    if (t < NBKT) lcnt[t] = 0;
    __syncthreads();
    int src[4], dst[4], rk[4], bkt[4];
    const int e0 = b * 1024;
    #pragma unroll
    for (int j = 0; j < 4; ++j) {
        int e = e0 + t + j * 256;
        if (e < NE) {
            src[j] = ei[e];
            dst[j] = ei[NE + e];
            bkt[j] = dst[j] >> 10;
            rk[j] = atomicAdd(&lcnt[bkt[j]], 1);
        } else rk[j] = -1;
    }
    __syncthreads();
    if (t < 64) {  // wave 0: exclusive scan of 49 bucket counts
        int v = (t < NBKT) ? lcnt[t] : 0;
        int x = v;
        #pragma unroll
        for (int off = 1; off < 64; off <<= 1) {
            int y = __shfl_up(x, off);
            if (t >= off) x += y;
        }
        if (t < NBKT) lboff[t] = x - v;
    }
    __syncthreads();
    #pragma unroll
    for (int j = 0; j < 4; ++j)
        if (rk[j] >= 0) lbuf[lboff[bkt[j]] + rk[j]] = make_int2(src[j], dst[j]);
    __syncthreads();
    const int total = lboff[NBKT - 1] + lcnt[NBKT - 1];
    for (int i = t; i < total; i += 256) seg[e0 + i] = lbuf[i];   // coalesced
    if (t < NBKT) { cnt2[b * NBKT + t] = lcnt[t]; boff2[b * NBKT + t] = lboff[t]; }
}

// ---- degree count from partitioned runs: one block per bucket, LDS histogram ----
__global__ __launch_bounds__(1024) void k_cnt(const int2* __restrict__ seg,
                                              const int* __restrict__ cnt2,
                                              const int* __restrict__ boff2,
                                              int* __restrict__ cnt) {
    __shared__ int lrk[1024];
    const int k = blockIdx.x, t = threadIdx.x;
    lrk[t] = 0;
    __syncthreads();
    const int node0 = k << 10;
    const int g = t >> 3, l = t & 7;   // 128 groups x 8 lanes
    for (int b = g; b < NSEG; b += 128) {
        const int n = cnt2[b * NBKT + k];
        const int base = b * 1024 + boff2[b * NBKT + k];
        for (int i = l; i < n; i += 8)
            atomicAdd(&lrk[seg[base + i].y - node0], 1);
    }
    __syncthreads();
    cnt[node0 + t] = lrk[t];   // coalesced full overwrite (pad nodes stay 0)
}

// ---- fill phase 2: one block per bucket; LDS ranks; writes confined to bucket window ----
__global__ __launch_bounds__(1024) void k_rank(const int2* __restrict__ seg,
                                               const int* __restrict__ cnt2,
                                               const int* __restrict__ boff2,
                                               const int* __restrict__ rowptr,
                                               int* __restrict__ csr_src) {
    __shared__ int lrk[1024];
    const int k = blockIdx.x, t = threadIdx.x;
    lrk[t] = 0;
    __syncthreads();
    const int node0 = k << 10;
    const int g = t >> 3, l = t & 7;   // 128 groups x 8 lanes
    for (int b = g; b < NSEG; b += 128) {
        const int n = cnt2[b * NBKT + k];
        const int base = b * 1024 + boff2[b * NBKT + k];
        for (int i = l; i < n; i += 8) {
            int2 e = seg[base + i];
            int rank = atomicAdd(&lrk[e.y - node0], 1);
            csr_src[rowptr[e.y] + rank] = e.x;
        }
    }
}

// ---- CSR scan phase A ----
__global__ __launch_bounds__(256) void k_scanA(const int* __restrict__ cnt,
                                               int* __restrict__ locpre, int* __restrict__ bsum) {
    const int b = blockIdx.x, t = threadIdx.x;
    const int base = b * 1024 + t * 4;
    int4 v = *reinterpret_cast<const int4*>(&cnt[base]);
    int s = v.x + v.y + v.z + v.w;
    __shared__ int sm[256];
    sm[t] = s;
    __syncthreads();
    for (int off = 1; off < 256; off <<= 1) {
        int y = (t >= off) ? sm[t - off] : 0;
        __syncthreads();
        sm[t] += y;
        __syncthreads();
    }
    int excl = sm[t] - s;
    locpre[base + 0] = excl;
    locpre[base + 1] = excl + v.x;
    locpre[base + 2] = excl + v.x + v.y;
    locpre[base + 3] = excl + v.x + v.y + v.z;
    if (t == 255) bsum[b] = sm[255];
}

// ---- CSR scan phase C ----
__global__ __launch_bounds__(256) void k_scanC(const int* __restrict__ cnt,
                                               const int* __restrict__ locpre,
                                               const int* __restrict__ bsum,
                                               int* __restrict__ rowptr,
                                               float* __restrict__ invc) {
    __shared__ int sm[64];
    const int b = blockIdx.x, t = threadIdx.x;
    const int nb = NPAD / 1024;  // 49
    if (t < nb) sm[t] = bsum[t];
    __syncthreads();
    int off = 0;
    for (int j = 0; j < b; ++j) off += sm[j];
    const int base = b * 1024 + t * 4;
    #pragma unroll
    for (int k = 0; k < 4; ++k) {
        int i = base + k;
        if (i < NN) {
            rowptr[i] = locpre[i] + off;
            invc[i] = 1.0f / fmaxf((float)cnt[i], 1.0f);
        }
    }
    if (b == 0 && t == 0) rowptr[NN] = NE;
}

// ---- prep: cast x -> bf16 + transposed bf16 weights ----
__global__ __launch_bounds__(256) void k_prep(const float* __restrict__ x, ushort* __restrict__ xb,
                                              const float* __restrict__ W1l, const float* __restrict__ W1r,
                                              const float* __restrict__ W2l, const float* __restrict__ W2r,
                                              ushort* __restrict__ Wt1, ushort* __restrict__ Wt2) {
    if (blockIdx.x < 3125) {
        unsigned g = blockIdx.x * 256u + threadIdx.x;  // < 800000 exactly
        const float4* p = reinterpret_cast<const float4*>(x) + (size_t)g * 2;
        float4 a = p[0], b = p[1];
        uint4 w;
        w.x = (uint)f2bf(a.x) | ((uint)f2bf(a.y) << 16);
        w.y = (uint)f2bf(a.z) | ((uint)f2bf(a.w) << 16);
        w.z = (uint)f2bf(b.x) | ((uint)f2bf(b.y) << 16);
        w.w = (uint)f2bf(b.z) | ((uint)f2bf(b.w) << 16);
        *reinterpret_cast<uint4*>(&xb[(size_t)g * 8]) = w;
    } else {
        int g = (blockIdx.x - 3125) * 256 + threadIdx.x;  // < 131072 exactly
        if (g < 65536) {
            int n = g >> 8, k = g & 255;
            float v = (k < 128) ? W1l[k * 256 + n] : W1r[(k - 128) * 256 + n];
            Wt1[n * 256 + k] = f2bf(v);
        } else {
            int g2 = g - 65536;
            int n = g2 >> 8, k = g2 & 255;
            float v = (n < 128) ? W2l[k * 128 + n] : W2r[k * 128 + (n - 128)];
            Wt2[n * 256 + k] = f2bf(v);
        }
    }
}

// ---- gather-aggregate over 128-ch bf16 rows, 4-way edge-parallel, 4x unrolled ----
template <bool FINAL>
__global__ __launch_bounds__(256) void k_agg128(const ushort* __restrict__ feat,
                                                const int* __restrict__ rowptr,
                                                const int* __restrict__ csr_src,
                                                const float* __restrict__ invc,
                                                const float* __restrict__ z,
                                                const float* __restrict__ bias,
                                                ushort* __restrict__ aggb,
                                                float* __restrict__ outf) {
    int gw = (blockIdx.x * 256 + threadIdx.x) >> 6;
    int lane = threadIdx.x & 63;
    if (gw >= NN) return;
    const int grp = lane >> 4, sl = lane & 15;
    const int beg = rowptr[gw], end = rowptr[gw + 1];
    float acc[8] = {};
    int e = beg + grp;
    for (; e + 12 < end; e += 16) {
        int s0 = csr_src[e];
        int s1 = csr_src[e + 4];
        int s2 = csr_src[e + 8];
        int s3 = csr_src[e + 12];
        uint4 u0 = *reinterpret_cast<const uint4*>(&feat[(size_t)s0 * 128 + sl * 8]);
        uint4 u1 = *reinterpret_cast<const uint4*>(&feat[(size_t)s1 * 128 + sl * 8]);
        uint4 u2 = *reinterpret_cast<const uint4*>(&feat[(size_t)s2 * 128 + sl * 8]);
        uint4 u3 = *reinterpret_cast<const uint4*>(&feat[(size_t)s3 * 128 + sl * 8]);
        acc[0] += bf2f((ushort)u0.x) + bf2f((ushort)u1.x) + bf2f((ushort)u2.x) + bf2f((ushort)u3.x);
        acc[1] += bf2f((ushort)(u0.x >> 16)) + bf2f((ushort)(u1.x >> 16)) + bf2f((ushort)(u2.x >> 16)) + bf2f((ushort)(u3.x >> 16));
        acc[2] += bf2f((ushort)u0.y) + bf2f((ushort)u1.y) + bf2f((ushort)u2.y) + bf2f((ushort)u3.y);
        acc[3] += bf2f((ushort)(u0.y >> 16)) + bf2f((ushort)(u1.y >> 16)) + bf2f((ushort)(u2.y >> 16)) + bf2f((ushort)(u3.y >> 16));
        acc[4] += bf2f((ushort)u0.z) + bf2f((ushort)u1.z) + bf2f((ushort)u2.z) + bf2f((ushort)u3.z);
        acc[5] += bf2f((ushort)(u0.z >> 16)) + bf2f((ushort)(u1.z >> 16)) + bf2f((ushort)(u2.z >> 16)) + bf2f((ushort)(u3.z >> 16));
        acc[6] += bf2f((ushort)u0.w) + bf2f((ushort)u1.w) + bf2f((ushort)u2.w) + bf2f((ushort)u3.w);
        acc[7] += bf2f((ushort)(u0.w >> 16)) + bf2f((ushort)(u1.w >> 16)) + bf2f((ushort)(u2.w >> 16)) + bf2f((ushort)(u3.w >> 16));
    }
    for (; e < end; e += 4) {
        int s0 = csr_src[e];
        uint4 u0 = *reinterpret_cast<const uint4*>(&feat[(size_t)s0 * 128 + sl * 8]);
        acc[0] += bf2f((ushort)u0.x); acc[1] += bf2f((ushort)(u0.x >> 16));
        acc[2] += bf2f((ushort)u0.y); acc[3] += bf2f((ushort)(u0.y >> 16));
        acc[4] += bf2f((ushort)u0.z); acc[5] += bf2f((ushort)(u0.z >> 16));
        acc[6] += bf2f((ushort)u0.w); acc[7] += bf2f((ushort)(u0.w >> 16));
    }
    #pragma unroll
    for (int i = 0; i < 8; ++i) {
        acc[i] += __shfl_xor(acc[i], 16);
        acc[i] += __shfl_xor(acc[i], 32);
    }
    if (grp == 0) {
        const float ic = invc[gw];
        if constexpr (FINAL) {
            const float* zp = &z[(size_t)gw * 128 + sl * 8];
            float4 z0 = *reinterpret_cast<const float4*>(zp);
            float4 z1 = *reinterpret_cast<const float4*>(zp + 4);
            float4 b0 = *reinterpret_cast<const float4*>(&bias[sl * 8]);
            float4 b1 = *reinterpret_cast<const float4*>(&bias[sl * 8 + 4]);
            float4 o0, o1;
            o0.x = fmaf(acc[0], ic, z0.x + b0.x);
            o0.y = fmaf(acc[1], ic, z0.y + b0.y);
            o0.z = fmaf(acc[2], ic, z0.z + b0.z);
            o0.w = fmaf(acc[3], ic, z0.w + b0.w);
            o1.x = fmaf(acc[4], ic, z1.x + b1.x);
            o1.y = fmaf(acc[5], ic, z1.y + b1.y);
            o1.z = fmaf(acc[6], ic, z1.z + b1.z);
            o1.w = fmaf(acc[7], ic, z1.w + b1.w);
            float* op = &outf[(size_t)gw * 128 + sl * 8];
            *reinterpret_cast<float4*>(op) = o0;
            *reinterpret_cast<float4*>(op + 4) = o1;
        } else {
            uint4 o;
            o.x = (uint)f2bf(acc[0] * ic) | ((uint)f2bf(acc[1] * ic) << 16);
            o.y = (uint)f2bf(acc[2] * ic) | ((uint)f2bf(acc[3] * ic) << 16);
            o.z = (uint)f2bf(acc[4] * ic) | ((uint)f2bf(acc[5] * ic) << 16);
            o.w = (uint)f2bf(acc[6] * ic) | ((uint)f2bf(acc[7] * ic) << 16);
            *reinterpret_cast<uint4*>(&aggb[(size_t)gw * 128 + sl * 8]) = o;
        }
    }
}

// ---- MFMA GEMM: out = [A1 | A2] @ Wt^T (+bias) ----
// 1D grid 1564 = 391 row-tiles x 4 col-tiles, XCD-chunked bijective swizzle:
// the 4 col-blocks sharing an A row-panel map to the SAME XCD -> A L2-resident.
// B slice preloaded to LDS once; K-loop barrier-free, A direct from global.
template <int K1, int K2, int NC, bool STATS, bool BN1, int OUTMODE>
__global__ __launch_bounds__(256, 4) void k_mm(const ushort* __restrict__ A1,
                                               const ushort* __restrict__ A2,
                                               const ushort* __restrict__ Wt,
                                               const float* __restrict__ bias,
                                               const float* __restrict__ sc,
                                               const float* __restrict__ sh,
                                               float* __restrict__ bnsums,
                                               ushort* __restrict__ outb,
                                               float* __restrict__ outf) {
    constexpr int KT = K1 + K2;
    constexpr int NIT = KT / 32;
    constexpr int BSTR = 264;            // LDS col stride (ushorts)
    constexpr int NWG = 1564, Q = NWG / 8, R = NWG % 8;   // 195, 4
    __shared__ ushort Bs[64 * BSTR];
    __shared__ float sred[4][4][16][2];
    const int t = threadIdx.x;
    const int lane = t & 63, wid = t >> 6;       // wid = wave row-group
    // XCD-chunked swizzle (bijective; dispatch d -> XCD d%8 assumption)
    const int bid = blockIdx.x;
    const int xcd = bid & 7, idx = bid >> 3;
    const int logical = (xcd < R ? xcd * (Q + 1) : R * (Q + 1) + (xcd - R) * Q) + idx;
    const int r0 = (logical >> 2) * 128, c0 = (logical & 3) * 64;
    const int lr = lane & 15, lg = lane >> 4;
    const int wrow = r0 + wid * 32;

    // B preload: 64 cols x KT k; coalesced
    #pragma unroll
    for (int i = 0; i < 64 * KT / 8 / 256; ++i) {
        int idx2 = i * 256 + t;
        int col = idx2 / (KT / 8);
        int slot = idx2 % (KT / 8);
        *reinterpret_cast<bf16x8*>(&Bs[col * BSTR + slot * 8]) =
            *reinterpret_cast<const bf16x8*>(&Wt[(size_t)(c0 + col) * KT + slot * 8]);
    }
    __syncthreads();

    f32x4 acc[2][4] = {};
    #pragma unroll
    for (int it = 0; it < NIT; ++it) {
        const int kt = it * 32;
        const ushort* __restrict__ Ap = (kt < K1) ? A1 : A2;
        const int AK = (kt < K1) ? K1 : K2;
        const int ak = (kt < K1) ? kt : kt - K1;
        bf16x8 af[2];
        #pragma unroll
        for (int mi = 0; mi < 2; ++mi) {
            af[mi] = *reinterpret_cast<const bf16x8*>(
                &Ap[(size_t)(wrow + mi * 16 + lr) * AK + ak + lg * 8]);
            if constexpr (BN1) {   // only used with K2==0 (ak == kt)
                const int cb = kt + lg * 8;
                float4 s0 = *reinterpret_cast<const float4*>(&sc[cb]);
                float4 s1 = *reinterpret_cast<const float4*>(&sc[cb + 4]);
                float4 h0 = *reinterpret_cast<const float4*>(&sh[cb]);
                float4 h1 = *reinterpret_cast<const float4*>(&sh[cb + 4]);
                float fsv[8] = {s0.x, s0.y, s0.z, s0.w, s1.x, s1.y, s1.z, s1.w};
                float fhv[8] = {h0.x, h0.y, h0.z, h0.w, h1.x, h1.y, h1.z, h1.w};
                #pragma unroll
                for (int j = 0; j < 8; ++j) {
                    float f = bf2f((ushort)af[mi][j]);
                    f = fmaxf(fmaf(f, fsv[j], fhv[j]), 0.f);
                    af[mi][j] = (short)f2bf(f);
                }
            }
        }
        bf16x8 bf[4];
        #pragma unroll
        for (int nj = 0; nj < 4; ++nj)
            bf[nj] = *reinterpret_cast<bf16x8*>(&Bs[(nj * 16 + lr) * BSTR + kt + lg * 8]);
        #pragma unroll
        for (int mi = 0; mi < 2; ++mi)
            #pragma unroll
            for (int nj = 0; nj < 4; ++nj)
                acc[mi][nj] = __builtin_amdgcn_mfma_f32_16x16x32_bf16(af[mi], bf[nj], acc[mi][nj], 0, 0, 0);
    }

    float ssum[4] = {}, s2sum[4] = {};
    #pragma unroll
    for (int nj = 0; nj < 4; ++nj) {
        const int col = c0 + nj * 16 + lr;
        float bv = 0.f;
        if constexpr (OUTMODE == 0) bv = bias[col];
        #pragma unroll
        for (int mi = 0; mi < 2; ++mi) {
            const int rbase = wrow + mi * 16;
            if (rbase + 16 > NN) continue;
            #pragma unroll
            for (int reg = 0; reg < 4; ++reg) {
                const int row = rbase + lg * 4 + reg;
                float d = acc[mi][nj][reg] + bv;
                if constexpr (STATS) { ssum[nj] += d; s2sum[nj] += d * d; }
                if constexpr (OUTMODE == 0) {
                    outb[(size_t)row * NC + col] = f2bf(d);
                } else {
                    if (col < 128) outb[(size_t)row * 128 + col] = f2bf(d);
                    else outf[(size_t)row * 128 + (col - 128)] = d;
                }
            }
        }
    }
    if constexpr (STATS) {
        #pragma unroll
        for (int nj = 0; nj < 4; ++nj) {
            ssum[nj] += __shfl_xor(ssum[nj], 16); ssum[nj] += __shfl_xor(ssum[nj], 32);
            s2sum[nj] += __shfl_xor(s2sum[nj], 16); s2sum[nj] += __shfl_xor(s2sum[nj], 32);
        }
        if (lane < 16) {
            #pragma unroll
            for (int nj = 0; nj < 4; ++nj) {
                sred[wid][nj][lane][0] = ssum[nj];
                sred[wid][nj][lane][1] = s2sum[nj];
            }
        }
        __syncthreads();
        if (wid == 0 && lane < 16) {
            #pragma unroll
            for (int nj = 0; nj < 4; ++nj) {
                const int col = c0 + nj * 16 + lane;
                float s = sred[0][nj][lane][0] + sred[1][nj][lane][0] + sred[2][nj][lane][0] + sred[3][nj][lane][0];
                float s2 = sred[0][nj][lane][1] + sred[1][nj][lane][1] + sred[2][nj][lane][1] + sred[3][nj][lane][1];
                atomAddF(&bnsums[col], s);
                atomAddF(&bnsums[256 + col], s2);
            }
        }
    }
}

// ---- BN finalize ----
__global__ void k_bnfin(const float* __restrict__ sums, const float* __restrict__ gamma,
                        const float* __restrict__ beta, float* __restrict__ sc,
                        float* __restrict__ sh) {
    int c = threadIdx.x;
    float mu = sums[c] * (1.0f / NN);
    float var = sums[256 + c] * (1.0f / NN) - mu * mu;
    float s = gamma[c] * rsqrtf(var + BN_EPS);
    sc[c] = s;
    sh[c] = beta[c] - mu * s;
}

extern "C" void kernel_launch(void* const* d_in, const int* in_sizes, int n_in,
                              void* d_out, int out_size, void* d_ws, size_t ws_size,
                              hipStream_t stream) {
    const float* x    = (const float*)d_in[0];
    const int*   ei   = (const int*)d_in[1];
    const float* W1l  = (const float*)d_in[2];
    const float* b1l  = (const float*)d_in[3];
    const float* W1r  = (const float*)d_in[4];
    const float* gam1 = (const float*)d_in[5];
    const float* bet1 = (const float*)d_in[6];
    const float* W2l  = (const float*)d_in[7];
    const float* b2l  = (const float*)d_in[8];
    const float* W2r  = (const float*)d_in[9];
    float* out = (float*)d_out;

    char* p = (char*)d_ws;
    ushort* xb   = (ushort*)p; p += (size_t)MPAD * 128 * 2;
    ushort* hb   = (ushort*)p; p += (size_t)MPAD * 256 * 2;
    ushort* aggb = (ushort*)p; p += (size_t)MPAD * 128 * 2;
    ushort* y2b  = (ushort*)p; p += (size_t)MPAD * 128 * 2;
    float*  zf   = (float*)p;  p += (size_t)MPAD * 128 * 4;
    ushort* Wt1  = (ushort*)p; p += 256 * 256 * 2;
    ushort* Wt2  = (ushort*)p; p += 256 * 256 * 2;
    int*   cnt    = (int*)p;   p += (size_t)NPAD * 4;
    float* bnsums = (float*)p; p += 512 * 4;
    float* bnsc   = (float*)p; p += 256 * 4;
    float* bnsh   = (float*)p; p += 256 * 4;
    float* invc   = (float*)p; p += (size_t)NPAD * 4;
    int*   rowptr = (int*)p;   p += (size_t)(NPAD + 4) * 4;
    int*   csr_src= (int*)p;   p += (size_t)NE * 4;
    int2*  seg    = (int2*)p;  p += (size_t)NE * 8;
    int*   cnt2   = (int*)p;   p += (size_t)NSEG * NBKT * 4;
    int*   boff2  = (int*)p;   p += (size_t)NSEG * NBKT * 4;
    int*   locpre = (int*)aggb;   // overlay: consumed by k_scanC before aggb written
    int*   bsum   = cnt2 + NSEG * NBKT - 64;  // unused tail? no — separate:
    bsum = (int*)p; p += 64 * 4;

    // zero bnsums (cnt no longer needs zeroing: k_cnt fully overwrites it)
    k_zero<<<1, 256, 0, stream>>>((int4*)bnsums);

    // CSR build: partition-sort -> degree-from-runs -> scan -> ranked fill
    k_part<<<NSEG, 256, 0, stream>>>(ei, seg, cnt2, boff2);
    k_cnt<<<NBKT, 1024, 0, stream>>>(seg, cnt2, boff2, cnt);
    k_scanA<<<NPAD / 1024, 256, 0, stream>>>(cnt, locpre, bsum);
    k_scanC<<<NPAD / 1024, 256, 0, stream>>>(cnt, locpre, bsum, rowptr, invc);
    k_rank<<<NBKT, 1024, 0, stream>>>(seg, cnt2, boff2, rowptr, csr_src);

    // bf16 precompute (castx + weight transpose fused)
    k_prep<<<3637, 256, 0, stream>>>(x, xb, W1l, W1r, W2l, W2r, Wt1, Wt2);

    // Layer 1: agg(x) -> GEMM [agg|x]@Wt1 (+bias, BN stats) -> bnfin
    k_agg128<false><<<12500, 256, 0, stream>>>(xb, rowptr, csr_src, invc, nullptr, nullptr, aggb, nullptr);
    k_mm<128, 128, 256, true, false, 0><<<1564, 256, 0, stream>>>(
        aggb, xb, Wt1, b1l, nullptr, nullptr, bnsums, hb, nullptr);
    k_bnfin<<<1, 256, 0, stream>>>(bnsums, gam1, bet1, bnsc, bnsh);

    // Layer 2 (swapped): [y2|z] = relu(bn(h)) @ [W2l|W2r]; out = mean(y2[src]) + z + b
    k_mm<256, 0, 256, false, true, 1><<<1564, 256, 0, stream>>>(
        hb, nullptr, Wt2, nullptr, bnsc, bnsh, nullptr, y2b, zf);
    k_agg128<true><<<12500, 256, 0, stream>>>(y2b, rowptr, csr_src, invc, zf, b2l, nullptr, out);
}

// Round 17
// 160.947 us; speedup vs baseline: 1.5718x; 1.1469x over previous
//
#include <hip/hip_runtime.h>

#define NN 50000
#define NPAD 50176   // 49*1024
#define MPAD 50048   // 782*64 (GEMM row tiles)
#define NE 800000
#define BN_EPS 1e-5f

#define NSEG 782     // edge chunks of 1024
#define NBKT 49      // dst buckets of 1024 nodes

typedef __attribute__((ext_vector_type(8))) short bf16x8;
typedef __attribute__((ext_vector_type(4))) float f32x4;

__device__ __forceinline__ void atomAddF(float* p, float v) { unsafeAtomicAdd(p, v); }

__device__ __forceinline__ float bf2f(ushort u) {
    union { uint i; float f; } v; v.i = ((uint)u) << 16; return v.f;
}
__device__ __forceinline__ ushort f2bf(float f) {
    union { uint i; float f; } v; v.f = f;
    uint u = v.i;
    return (ushort)((u + 0x7FFFu + ((u >> 16) & 1u)) >> 16);  // RNE
}

// ---- fused: partition-sort (blocks 0..781) + bf16 prep (blocks 782..4418) + bnsums zero ----
__global__ __launch_bounds__(256) void k_pp(const int* __restrict__ ei,
                                            int2* __restrict__ seg,
                                            int* __restrict__ cnt2,
                                            int* __restrict__ boff2,
                                            const float* __restrict__ x, ushort* __restrict__ xb,
                                            const float* __restrict__ W1l, const float* __restrict__ W1r,
                                            const float* __restrict__ W2l, const float* __restrict__ W2r,
                                            ushort* __restrict__ Wt1, ushort* __restrict__ Wt2,
                                            float* __restrict__ bnsums) {
    const int t = threadIdx.x;
    if (blockIdx.x < NSEG) {
        // ---- partition-sort of 1024 edges by dst-bucket ----
        __shared__ int lcnt[NBKT];
        __shared__ int lboff[NBKT];
        __shared__ int2 lbuf[1024];
        const int b = blockIdx.x;
        if (b == 0 && t < 128) reinterpret_cast<int4*>(bnsums)[t] = make_int4(0, 0, 0, 0);
        if (t < NBKT) lcnt[t] = 0;
        __syncthreads();
        int src[4], dst[4], rk[4], bkt[4];
        const int e0 = b * 1024;
        #pragma unroll
        for (int j = 0; j < 4; ++j) {
            int e = e0 + t + j * 256;
            if (e < NE) {
                src[j] = ei[e];
                dst[j] = ei[NE + e];
                bkt[j] = dst[j] >> 10;
                rk[j] = atomicAdd(&lcnt[bkt[j]], 1);
            } else rk[j] = -1;
        }
        __syncthreads();
        if (t < 64) {  // wave 0: exclusive scan of 49 bucket counts
            int v = (t < NBKT) ? lcnt[t] : 0;
            int y = v;
            #pragma unroll
            for (int off = 1; off < 64; off <<= 1) {
                int z = __shfl_up(y, off);
                if (t >= off) y += z;
            }
            if (t < NBKT) lboff[t] = y - v;
        }
        __syncthreads();
        #pragma unroll
        for (int j = 0; j < 4; ++j)
            if (rk[j] >= 0) lbuf[lboff[bkt[j]] + rk[j]] = make_int2(src[j], dst[j]);
        __syncthreads();
        const int total = lboff[NBKT - 1] + lcnt[NBKT - 1];
        for (int i = t; i < total; i += 256) seg[e0 + i] = lbuf[i];
        if (t < NBKT) { cnt2[b * NBKT + t] = lcnt[t]; boff2[b * NBKT + t] = lboff[t]; }
    } else {
        const int pb = blockIdx.x - NSEG;
        if (pb < 3125) {
            unsigned g = pb * 256u + t;  // < 800000 exactly
            const float4* p = reinterpret_cast<const float4*>(x) + (size_t)g * 2;
            float4 a = p[0], b2 = p[1];
            uint4 w;
            w.x = (uint)f2bf(a.x) | ((uint)f2bf(a.y) << 16);
            w.y = (uint)f2bf(a.z) | ((uint)f2bf(a.w) << 16);
            w.z = (uint)f2bf(b2.x) | ((uint)f2bf(b2.y) << 16);
            w.w = (uint)f2bf(b2.z) | ((uint)f2bf(b2.w) << 16);
            *reinterpret_cast<uint4*>(&xb[(size_t)g * 8]) = w;
        } else {
            int g = (pb - 3125) * 256 + t;  // < 131072 exactly
            if (g < 65536) {
                int n = g >> 8, k = g & 255;
                float v = (k < 128) ? W1l[k * 256 + n] : W1r[(k - 128) * 256 + n];
                Wt1[n * 256 + k] = f2bf(v);
            } else {
                int g2 = g - 65536;
                int n = g2 >> 8, k = g2 & 255;
                float v = (n < 128) ? W2l[k * 128 + n] : W2r[k * 128 + (n - 128)];
                Wt2[n * 256 + k] = f2bf(v);
            }
        }
    }
}

// ---- degree histogram + block scan: locpre (bucket-local exclusive) + bsum ----
__global__ __launch_bounds__(1024) void k_cntA(const int2* __restrict__ seg,
                                               const int* __restrict__ cnt2,
                                               const int* __restrict__ boff2,
                                               int* __restrict__ locpre,
                                               int* __restrict__ bsum) {
    __shared__ int lrk[1024];
    __shared__ int sm[1024];
    const int k = blockIdx.x, t = threadIdx.x;
    lrk[t] = 0;
    __syncthreads();
    const int node0 = k << 10;
    const int g = t >> 3, l = t & 7;
    for (int b = g; b < NSEG; b += 128) {
        const int n = cnt2[b * NBKT + k];
        const int base = b * 1024 + boff2[b * NBKT + k];
        for (int i = l; i < n; i += 8)
            atomicAdd(&lrk[seg[base + i].y - node0], 1);
    }
    __syncthreads();
    int v = lrk[t];
    sm[t] = v;
    __syncthreads();
    for (int off = 1; off < 1024; off <<= 1) {
        int y = (t >= off) ? sm[t - off] : 0;
        __syncthreads();
        sm[t] += y;
        __syncthreads();
    }
    locpre[node0 + t] = sm[t] - v;   // exclusive within bucket
    if (t == 1023) bsum[k] = sm[1023];
}

// ---- rowptr/invc emit + ranked fill (one block per bucket, LDS row bases) ----
__global__ __launch_bounds__(1024) void k_rankC(const int2* __restrict__ seg,
                                                const int* __restrict__ cnt2,
                                                const int* __restrict__ boff2,
                                                const int* __restrict__ locpre,
                                                const int* __restrict__ bsum,
                                                int* __restrict__ rowptr,
                                                float* __restrict__ invc,
                                                int* __restrict__ csr_src) {
    __shared__ int lbase[1024];
    __shared__ int lrk[1024];
    __shared__ int soff_sh, stot_sh;
    const int k = blockIdx.x, t = threadIdx.x;
    if (t < 64) {   // wave 0: soff = sum bsum[0..k-1]
        int v = (t < k) ? bsum[t] : 0;
        #pragma unroll
        for (int off = 1; off < 64; off <<= 1) v += __shfl_xor(v, off);
        if (t == 0) { soff_sh = v; stot_sh = bsum[k]; }
    }
    lrk[t] = 0;
    __syncthreads();
    const int soff = soff_sh, stot = stot_sh;
    const int node0 = k << 10;
    const int base = locpre[node0 + t] + soff;
    lbase[t] = base;
    __syncthreads();
    const int node = node0 + t;
    if (node <= NN) {
        // for node==NN (pad region of last bucket) base == NE (all counts before are real)
        if (node < NN || node == NN) rowptr[node] = base;
        if (node < NN) {
            int nextb = (t < 1023) ? lbase[t + 1] : soff + stot;
            invc[node] = 1.0f / fmaxf((float)(nextb - base), 1.0f);
        }
    }
    const int g = t >> 3, l = t & 7;
    for (int b = g; b < NSEG; b += 128) {
        const int n = cnt2[b * NBKT + k];
        const int sb = b * 1024 + boff2[b * NBKT + k];
        for (int i = l; i < n; i += 8) {
            int2 e = seg[sb + i];
            int li = e.y - node0;
            int rank = atomicAdd(&lrk[li], 1);
            csr_src[lbase[li] + rank] = e.x;
        }
    }
}

// ---- gather-aggregate over 128-ch bf16 rows, 4-way edge-parallel, 4x unrolled ----
template <bool FINAL>
__global__ __launch_bounds__(256) void k_agg128(const ushort* __restrict__ feat,
                                                const int* __restrict__ rowptr,
                                                const int* __restrict__ csr_src,
                                                const float* __restrict__ invc,
                                                const float* __restrict__ z,
                                                const float* __restrict__ bias,
                                                ushort* __restrict__ aggb,
                                                float* __restrict__ outf) {
    int gw = (blockIdx.x * 256 + threadIdx.x) >> 6;
    int lane = threadIdx.x & 63;
    if (gw >= NN) return;
    const int grp = lane >> 4, sl = lane & 15;
    const int beg = rowptr[gw], end = rowptr[gw + 1];
    float acc[8] = {};
    int e = beg + grp;
    for (; e + 12 < end; e += 16) {
        int s0 = csr_src[e];
        int s1 = csr_src[e + 4];
        int s2 = csr_src[e + 8];
        int s3 = csr_src[e + 12];
        uint4 u0 = *reinterpret_cast<const uint4*>(&feat[(size_t)s0 * 128 + sl * 8]);
        uint4 u1 = *reinterpret_cast<const uint4*>(&feat[(size_t)s1 * 128 + sl * 8]);
        uint4 u2 = *reinterpret_cast<const uint4*>(&feat[(size_t)s2 * 128 + sl * 8]);
        uint4 u3 = *reinterpret_cast<const uint4*>(&feat[(size_t)s3 * 128 + sl * 8]);
        acc[0] += bf2f((ushort)u0.x) + bf2f((ushort)u1.x) + bf2f((ushort)u2.x) + bf2f((ushort)u3.x);
        acc[1] += bf2f((ushort)(u0.x >> 16)) + bf2f((ushort)(u1.x >> 16)) + bf2f((ushort)(u2.x >> 16)) + bf2f((ushort)(u3.x >> 16));
        acc[2] += bf2f((ushort)u0.y) + bf2f((ushort)u1.y) + bf2f((ushort)u2.y) + bf2f((ushort)u3.y);
        acc[3] += bf2f((ushort)(u0.y >> 16)) + bf2f((ushort)(u1.y >> 16)) + bf2f((ushort)(u2.y >> 16)) + bf2f((ushort)(u3.y >> 16));
        acc[4] += bf2f((ushort)u0.z) + bf2f((ushort)u1.z) + bf2f((ushort)u2.z) + bf2f((ushort)u3.z);
        acc[5] += bf2f((ushort)(u0.z >> 16)) + bf2f((ushort)(u1.z >> 16)) + bf2f((ushort)(u2.z >> 16)) + bf2f((ushort)(u3.z >> 16));
        acc[6] += bf2f((ushort)u0.w) + bf2f((ushort)u1.w) + bf2f((ushort)u2.w) + bf2f((ushort)u3.w);
        acc[7] += bf2f((ushort)(u0.w >> 16)) + bf2f((ushort)(u1.w >> 16)) + bf2f((ushort)(u2.w >> 16)) + bf2f((ushort)(u3.w >> 16));
    }
    for (; e < end; e += 4) {
        int s0 = csr_src[e];
        uint4 u0 = *reinterpret_cast<const uint4*>(&feat[(size_t)s0 * 128 + sl * 8]);
        acc[0] += bf2f((ushort)u0.x); acc[1] += bf2f((ushort)(u0.x >> 16));
        acc[2] += bf2f((ushort)u0.y); acc[3] += bf2f((ushort)(u0.y >> 16));
        acc[4] += bf2f((ushort)u0.z); acc[5] += bf2f((ushort)(u0.z >> 16));
        acc[6] += bf2f((ushort)u0.w); acc[7] += bf2f((ushort)(u0.w >> 16));
    }
    #pragma unroll
    for (int i = 0; i < 8; ++i) {
        acc[i] += __shfl_xor(acc[i], 16);
        acc[i] += __shfl_xor(acc[i], 32);
    }
    if (grp == 0) {
        const float ic = invc[gw];
        if constexpr (FINAL) {
            const float* zp = &z[(size_t)gw * 128 + sl * 8];
            float4 z0 = *reinterpret_cast<const float4*>(zp);
            float4 z1 = *reinterpret_cast<const float4*>(zp + 4);
            float4 b0 = *reinterpret_cast<const float4*>(&bias[sl * 8]);
            float4 b1 = *reinterpret_cast<const float4*>(&bias[sl * 8 + 4]);
            float4 o0, o1;
            o0.x = fmaf(acc[0], ic, z0.x + b0.x);
            o0.y = fmaf(acc[1], ic, z0.y + b0.y);
            o0.z = fmaf(acc[2], ic, z0.z + b0.z);
            o0.w = fmaf(acc[3], ic, z0.w + b0.w);
            o1.x = fmaf(acc[4], ic, z1.x + b1.x);
            o1.y = fmaf(acc[5], ic, z1.y + b1.y);
            o1.z = fmaf(acc[6], ic, z1.z + b1.z);
            o1.w = fmaf(acc[7], ic, z1.w + b1.w);
            float* op = &outf[(size_t)gw * 128 + sl * 8];
            *reinterpret_cast<float4*>(op) = o0;
            *reinterpret_cast<float4*>(op + 4) = o1;
        } else {
            uint4 o;
            o.x = (uint)f2bf(acc[0] * ic) | ((uint)f2bf(acc[1] * ic) << 16);
            o.y = (uint)f2bf(acc[2] * ic) | ((uint)f2bf(acc[3] * ic) << 16);
            o.z = (uint)f2bf(acc[4] * ic) | ((uint)f2bf(acc[5] * ic) << 16);
            o.w = (uint)f2bf(acc[6] * ic) | ((uint)f2bf(acc[7] * ic) << 16);
            *reinterpret_cast<uint4*>(&aggb[(size_t)gw * 128 + sl * 8]) = o;
        }
    }
}

// ---- MFMA GEMM: out = [A1 | A2] @ Wt^T (+bias) ----
// 1D grid 1564, XCD-chunked swizzle; B slice in LDS once; barrier-free K-loop.
// BN1: BN scale/shift computed IN-KERNEL from bnsums+gamma+beta (fused bnfin).
template <int K1, int K2, int NC, bool STATS, bool BN1, int OUTMODE>
__global__ __launch_bounds__(256, 4) void k_mm(const ushort* __restrict__ A1,
                                               const ushort* __restrict__ A2,
                                               const ushort* __restrict__ Wt,
                                               const float* __restrict__ bias,
                                               const float* __restrict__ gamma,
                                               const float* __restrict__ beta,
                                               float* __restrict__ bnsums,
                                               ushort* __restrict__ outb,
                                               float* __restrict__ outf) {
    constexpr int KT = K1 + K2;
    constexpr int NIT = KT / 32;
    constexpr int BSTR = 264;            // LDS col stride (ushorts)
    constexpr int NWG = 1564, Q = NWG / 8, R = NWG % 8;   // 195, 4
    __shared__ ushort Bs[64 * BSTR];
    __shared__ float sred[4][4][16][2];
    __shared__ float scs[256], shs[256];
    const int t = threadIdx.x;
    const int lane = t & 63, wid = t >> 6;
    const int bid = blockIdx.x;
    const int xcd = bid & 7, idx = bid >> 3;
    const int logical = (xcd < R ? xcd * (Q + 1) : R * (Q + 1) + (xcd - R) * Q) + idx;
    const int r0 = (logical >> 2) * 128, c0 = (logical & 3) * 64;
    const int lr = lane & 15, lg = lane >> 4;
    const int wrow = r0 + wid * 32;

    if constexpr (BN1) {   // fused bnfin: per-block compute of BN scale/shift
        float mu = bnsums[t & 255] * (1.0f / NN);
        float var = bnsums[256 + (t & 255)] * (1.0f / NN) - mu * mu;
        float s = gamma[t & 255] * rsqrtf(var + BN_EPS);
        scs[t & 255] = s;
        shs[t & 255] = beta[t & 255] - mu * s;
    }
    // B preload: 64 cols x KT k; coalesced
    #pragma unroll
    for (int i = 0; i < 64 * KT / 8 / 256; ++i) {
        int idx2 = i * 256 + t;
        int col = idx2 / (KT / 8);
        int slot = idx2 % (KT / 8);
        *reinterpret_cast<bf16x8*>(&Bs[col * BSTR + slot * 8]) =
            *reinterpret_cast<const bf16x8*>(&Wt[(size_t)(c0 + col) * KT + slot * 8]);
    }
    __syncthreads();

    f32x4 acc[2][4] = {};
    #pragma unroll
    for (int it = 0; it < NIT; ++it) {
        const int kt = it * 32;
        const ushort* __restrict__ Ap = (kt < K1) ? A1 : A2;
        const int AK = (kt < K1) ? K1 : K2;
        const int ak = (kt < K1) ? kt : kt - K1;
        bf16x8 af[2];
        #pragma unroll
        for (int mi = 0; mi < 2; ++mi) {
            af[mi] = *reinterpret_cast<const bf16x8*>(
                &Ap[(size_t)(wrow + mi * 16 + lr) * AK + ak + lg * 8]);
            if constexpr (BN1) {   // only used with K2==0 (ak == kt)
                const int cb = kt + lg * 8;
                #pragma unroll
                for (int j = 0; j < 8; ++j) {
                    float f = bf2f((ushort)af[mi][j]);
                    f = fmaxf(fmaf(f, scs[cb + j], shs[cb + j]), 0.f);
                    af[mi][j] = (short)f2bf(f);
                }
            }
        }
        bf16x8 bf[4];
        #pragma unroll
        for (int nj = 0; nj < 4; ++nj)
            bf[nj] = *reinterpret_cast<bf16x8*>(&Bs[(nj * 16 + lr) * BSTR + kt + lg * 8]);
        #pragma unroll
        for (int mi = 0; mi < 2; ++mi)
            #pragma unroll
            for (int nj = 0; nj < 4; ++nj)
                acc[mi][nj] = __builtin_amdgcn_mfma_f32_16x16x32_bf16(af[mi], bf[nj], acc[mi][nj], 0, 0, 0);
    }

    float ssum[4] = {}, s2sum[4] = {};
    #pragma unroll
    for (int nj = 0; nj < 4; ++nj) {
        const int col = c0 + nj * 16 + lr;
        float bv = 0.f;
        if constexpr (OUTMODE == 0) bv = bias[col];
        #pragma unroll
        for (int mi = 0; mi < 2; ++mi) {
            const int rbase = wrow + mi * 16;
            if (rbase + 16 > NN) continue;
            #pragma unroll
            for (int reg = 0; reg < 4; ++reg) {
                const int row = rbase + lg * 4 + reg;
                float d = acc[mi][nj][reg] + bv;
                if constexpr (STATS) { ssum[nj] += d; s2sum[nj] += d * d; }
                if constexpr (OUTMODE == 0) {
                    outb[(size_t)row * NC + col] = f2bf(d);
                } else {
                    if (col < 128) outb[(size_t)row * 128 + col] = f2bf(d);
                    else outf[(size_t)row * 128 + (col - 128)] = d;
                }
            }
        }
    }
    if constexpr (STATS) {
        #pragma unroll
        for (int nj = 0; nj < 4; ++nj) {
            ssum[nj] += __shfl_xor(ssum[nj], 16); ssum[nj] += __shfl_xor(ssum[nj], 32);
            s2sum[nj] += __shfl_xor(s2sum[nj], 16); s2sum[nj] += __shfl_xor(s2sum[nj], 32);
        }
        if (lane < 16) {
            #pragma unroll
            for (int nj = 0; nj < 4; ++nj) {
                sred[wid][nj][lane][0] = ssum[nj];
                sred[wid][nj][lane][1] = s2sum[nj];
            }
        }
        __syncthreads();
        if (wid == 0 && lane < 16) {
            #pragma unroll
            for (int nj = 0; nj < 4; ++nj) {
                const int col = c0 + nj * 16 + lane;
                float s = sred[0][nj][lane][0] + sred[1][nj][lane][0] + sred[2][nj][lane][0] + sred[3][nj][lane][0];
                float s2 = sred[0][nj][lane][1] + sred[1][nj][lane][1] + sred[2][nj][lane][1] + sred[3][nj][lane][1];
                atomAddF(&bnsums[col], s);
                atomAddF(&bnsums[256 + col], s2);
            }
        }
    }
}

extern "C" void kernel_launch(void* const* d_in, const int* in_sizes, int n_in,
                              void* d_out, int out_size, void* d_ws, size_t ws_size,
                              hipStream_t stream) {
    const float* x    = (const float*)d_in[0];
    const int*   ei   = (const int*)d_in[1];
    const float* W1l  = (const float*)d_in[2];
    const float* b1l  = (const float*)d_in[3];
    const float* W1r  = (const float*)d_in[4];
    const float* gam1 = (const float*)d_in[5];
    const float* bet1 = (const float*)d_in[6];
    const float* W2l  = (const float*)d_in[7];
    const float* b2l  = (const float*)d_in[8];
    const float* W2r  = (const float*)d_in[9];
    float* out = (float*)d_out;

    char* p = (char*)d_ws;
    ushort* xb   = (ushort*)p; p += (size_t)MPAD * 128 * 2;
    ushort* hb   = (ushort*)p; p += (size_t)MPAD * 256 * 2;
    ushort* aggb = (ushort*)p; p += (size_t)MPAD * 128 * 2;
    ushort* y2b  = (ushort*)p; p += (size_t)MPAD * 128 * 2;
    float*  zf   = (float*)p;  p += (size_t)MPAD * 128 * 4;
    ushort* Wt1  = (ushort*)p; p += 256 * 256 * 2;
    ushort* Wt2  = (ushort*)p; p += 256 * 256 * 2;
    float* bnsums = (float*)p; p += 512 * 4 + 2048;
    float* invc   = (float*)p; p += (size_t)NPAD * 4;
    int*   rowptr = (int*)p;   p += (size_t)(NPAD + 4) * 4;
    int*   csr_src= (int*)p;   p += (size_t)NE * 4;
    int2*  seg    = (int2*)p;  p += (size_t)NE * 8;
    int*   cnt2   = (int*)p;   p += (size_t)NSEG * NBKT * 4;
    int*   boff2  = (int*)p;   p += (size_t)NSEG * NBKT * 4;
    int*   bsum   = (int*)p;   p += 64 * 4;
    int*   locpre = (int*)aggb;   // overlay: consumed by k_rankC before aggb written

    // 1: partition + bf16 prep + bnsums zero (independent parts co-scheduled)
    k_pp<<<NSEG + 3637, 256, 0, stream>>>(ei, seg, cnt2, boff2,
                                          x, xb, W1l, W1r, W2l, W2r, Wt1, Wt2, bnsums);
    // 2: degree histogram + block scan -> locpre/bsum
    k_cntA<<<NBKT, 1024, 0, stream>>>(seg, cnt2, boff2, locpre, bsum);
    // 3: rowptr/invc emit + ranked fill
    k_rankC<<<NBKT, 1024, 0, stream>>>(seg, cnt2, boff2, locpre, bsum, rowptr, invc, csr_src);

    // 4: Layer 1 aggregate
    k_agg128<false><<<12500, 256, 0, stream>>>(xb, rowptr, csr_src, invc, nullptr, nullptr, aggb, nullptr);
    // 5: GEMM [agg|x]@Wt1 + bias, fused BN stats
    k_mm<128, 128, 256, true, false, 0><<<1564, 256, 0, stream>>>(
        aggb, xb, Wt1, b1l, nullptr, nullptr, bnsums, hb, nullptr);
    // 6: GEMM relu(bn(h))@[W2l|W2r] with fused bnfin -> y2 (bf16) + z (fp32)
    k_mm<256, 0, 256, false, true, 1><<<1564, 256, 0, stream>>>(
        hb, nullptr, Wt2, nullptr, gam1, bet1, bnsums, y2b, zf);
    // 7: Layer 2 aggregate + z + bias -> out
    k_agg128<true><<<12500, 256, 0, stream>>>(y2b, rowptr, csr_src, invc, zf, b2l, nullptr, out);
}